// Round 5
// baseline (1739.070 us; speedup 1.0000x reference)
//
#include <hip/hip_runtime.h>

#define H_N   100000
#define E_N   200000
#define NI_N  1000000
#define LN_EPS 1e-5f

// Edge buckets: 64 edges each -> one MLP tile per bucket. 200000/64 = 3125 exactly.
#define NBUCK_E 3125
// Node buckets: 64 nodes each. ceil(100000/64) = 1563.
#define NBUCK_H 1563
#define SUBCAP_E 128       // per-XCD sub-bucket cap (mean 40, sigma ~6)
#define SUBCAP_H 192       // per-XCD sub-bucket cap (mean 80, sigma ~9)
#define CAP_E 512          // total per-bucket cap (mean 320, sigma ~18)
#define CAP_H 1024         // total per-bucket cap (mean 640, sigma ~25)
#define BCNT_PAD 16        // one counter per 64B line: kills same-line atomic RMW serialization

typedef __attribute__((ext_vector_type(8))) short bf16x8;
typedef __attribute__((ext_vector_type(4))) float floatx4;
typedef __attribute__((ext_vector_type(4))) int intx4;

__device__ inline unsigned short f2bf(float f) {
  unsigned u = __builtin_bit_cast(unsigned, f);
  u += 0x7fffu + ((u >> 16) & 1u);           // round-to-nearest-even
  return (unsigned short)(u >> 16);
}
__device__ inline float bf2f(unsigned short s) {
  unsigned u = ((unsigned)s) << 16;
  return __builtin_bit_cast(float, u);
}
__device__ inline unsigned get_xcc() {
  unsigned x;
  asm volatile("s_getreg_b32 %0, hwreg(HW_REG_XCC_ID)" : "=s"(x));
  return x & 7;
}
// 8 consecutive f32 from LDS -> scaled bf16x8 fragment
__device__ inline bf16x8 cvt_frag(const float* p, float inv) {
  bf16x8 r;
#pragma unroll
  for (int i = 0; i < 8; ++i) r[i] = (short)f2bf(p[i] * inv);
  return r;
}

// ---------------------------------------------------------------------------
// fp32 -> bf16 conversion, 4 elements/thread
// ---------------------------------------------------------------------------
__global__ __launch_bounds__(256) void k_cvt_bf16(const float4* __restrict__ src,
                                                  unsigned short* __restrict__ dst,
                                                  int n4) {
  int i = blockIdx.x * 256 + threadIdx.x;
  if (i >= n4) return;
  float4 v = src[i];
  union { unsigned short us[4]; unsigned long long u64; } p;
  p.us[0] = f2bf(v.x); p.us[1] = f2bf(v.y);
  p.us[2] = f2bf(v.z); p.us[3] = f2bf(v.w);
  *(unsigned long long*)(dst + (size_t)i * 4) = p.u64;
}

// ---------------------------------------------------------------------------
// Bucket binning, XCD-local, 4 incidences/thread.
// ---------------------------------------------------------------------------
__global__ __launch_bounds__(256) void k_bucket(
    const int* __restrict__ fg, const int* __restrict__ res,
    int* __restrict__ bcnt_e, int* __restrict__ bcnt_h,
    unsigned* __restrict__ pairs_e, unsigned* __restrict__ pairs_h) {
  int i0 = (blockIdx.x * 256 + threadIdx.x) * 4;
  if (i0 >= NI_N) return;
  unsigned xcc = get_xcc();
  intx4 f4 = __builtin_nontemporal_load((const intx4*)(fg + i0));
  intx4 r4 = __builtin_nontemporal_load((const intx4*)(res + i0));
#pragma unroll
  for (int j = 0; j < 4; ++j) {
    int f = f4[j], r = r4[j];
    int be = r >> 6, se = r & 63;
    int pe = atomicAdd(bcnt_e + ((size_t)xcc * NBUCK_E + be) * BCNT_PAD, 1);
    if (pe < SUBCAP_E)
      pairs_e[((size_t)xcc * NBUCK_E + be) * SUBCAP_E + pe] =
          ((unsigned)se << 24) | (unsigned)f;
    int bh = f >> 6, sh = f & 63;
    int ph = atomicAdd(bcnt_h + ((size_t)xcc * NBUCK_H + bh) * BCNT_PAD, 1);
    if (ph < SUBCAP_H)
      pairs_h[((size_t)xcc * NBUCK_H + bh) * SUBCAP_H + ph] =
          ((unsigned)sh << 24) | (unsigned)r;
  }
}

// ---------------------------------------------------------------------------
// Fused edge: concat -> wave-parallel gather with LDS f32 atomic accumulate
// (no sort/scan/scatter) -> edge MLP. 1/cnt + f32->bf16 fold into the MFMA
// A-fragment load. accS f32 tile doubles as h1 bf16 tile (barrier-separated).
// Gather: each wave takes entries j==wave (mod 4), unroll 4 -> 4 independent
// full-row (dword/lane) loads in flight per wave.
// ---------------------------------------------------------------------------
__global__ __launch_bounds__(256, 4) void k_edge_fused(
    const unsigned short* __restrict__ xh, const short* __restrict__ attr_bf,
    const unsigned* __restrict__ pairs, const int* __restrict__ bcnt,
    const short* __restrict__ w1, const float* __restrict__ b1,
    const short* __restrict__ w2, const float* __restrict__ b2,
    unsigned short* __restrict__ edge_msg) {
  __shared__ float accS[64][132];      // 33792 B; h1 bf16 tile overlays later
  __shared__ unsigned raw[CAP_E];      // 2048 B
  __shared__ int cnts[64];
  short (*h1s)[136] = (short(*)[136])accS;

  const int b = blockIdx.x;
  const int t = threadIdx.x;

  for (int i = t; i < 64 * 132; i += 256) ((float*)accS)[i] = 0.f;
  if (t < 64) cnts[t] = 0;

  // ---- concat 8 per-XCD sub-lists ----
  int total = 0;
#pragma unroll
  for (int x = 0; x < 8; ++x) {
    int c = min(bcnt[((size_t)x * NBUCK_E + b) * BCNT_PAD], SUBCAP_E);
    const unsigned* src = pairs + ((size_t)x * NBUCK_E + b) * SUBCAP_E;
    for (int j = t; j < c; j += 256) {
      int d = total + j;
      if (d < CAP_E) raw[d] = src[j];
    }
    total += c;
  }
  const int cnt = min(total, CAP_E);
  __syncthreads();

  // ---- counts (for means) ----
  for (int j = t; j < cnt; j += 256)
    atomicAdd(&cnts[raw[j] >> 24], 1);

  // ---- wave-parallel gather-accumulate ----
  const int wave = t >> 6, lane = t & 63;
  {
    const char* base = (const char*)xh;
    int j = wave;
    for (; j + 12 < cnt; j += 16) {
      unsigned p0 = raw[j], p1 = raw[j + 4], p2 = raw[j + 8], p3 = raw[j + 12];
      unsigned v0 = *(const unsigned*)(base + ((size_t)(p0 & 0xFFFFFFu) << 8) + lane * 4);
      unsigned v1 = *(const unsigned*)(base + ((size_t)(p1 & 0xFFFFFFu) << 8) + lane * 4);
      unsigned v2 = *(const unsigned*)(base + ((size_t)(p2 & 0xFFFFFFu) << 8) + lane * 4);
      unsigned v3 = *(const unsigned*)(base + ((size_t)(p3 & 0xFFFFFFu) << 8) + lane * 4);
      int s0 = p0 >> 24, s1 = p1 >> 24, s2 = p2 >> 24, s3 = p3 >> 24;
      atomicAdd(&accS[s0][lane * 2],     bf2f((unsigned short)(v0 & 0xffffu)));
      atomicAdd(&accS[s0][lane * 2 + 1], bf2f((unsigned short)(v0 >> 16)));
      atomicAdd(&accS[s1][lane * 2],     bf2f((unsigned short)(v1 & 0xffffu)));
      atomicAdd(&accS[s1][lane * 2 + 1], bf2f((unsigned short)(v1 >> 16)));
      atomicAdd(&accS[s2][lane * 2],     bf2f((unsigned short)(v2 & 0xffffu)));
      atomicAdd(&accS[s2][lane * 2 + 1], bf2f((unsigned short)(v2 >> 16)));
      atomicAdd(&accS[s3][lane * 2],     bf2f((unsigned short)(v3 & 0xffffu)));
      atomicAdd(&accS[s3][lane * 2 + 1], bf2f((unsigned short)(v3 >> 16)));
    }
    for (; j < cnt; j += 4) {
      unsigned p0 = raw[j];
      unsigned v0 = *(const unsigned*)(base + ((size_t)(p0 & 0xFFFFFFu) << 8) + lane * 4);
      int s0 = p0 >> 24;
      atomicAdd(&accS[s0][lane * 2],     bf2f((unsigned short)(v0 & 0xffffu)));
      atomicAdd(&accS[s0][lane * 2 + 1], bf2f((unsigned short)(v0 >> 16)));
    }
  }
  __syncthreads();

  // ---- edge MLP (A from accS f32, scaled+converted at load) ----
  const int row  = lane & 15;
  const int quad = lane >> 4;
  const int e0   = b * 64;
  const int cb   = wave * 32;

  float invr[4];
#pragma unroll
  for (int m = 0; m < 4; ++m) {
    int c = cnts[m * 16 + row];
    invr[m] = c > 0 ? 1.0f / (float)c : 0.0f;
  }

  bf16x8 B1[2][6];
#pragma unroll
  for (int nl = 0; nl < 2; ++nl)
#pragma unroll
    for (int ks = 0; ks < 6; ++ks)
      B1[nl][ks] = *(const bf16x8*)(w1 + (size_t)(cb + nl * 16 + row) * 192 +
                                    ks * 32 + quad * 8);

  floatx4 acc[4][2];
#pragma unroll
  for (int m = 0; m < 4; ++m)
#pragma unroll
    for (int nl = 0; nl < 2; ++nl) acc[m][nl] = (floatx4){0.f, 0.f, 0.f, 0.f};

#pragma unroll
  for (int ks = 0; ks < 6; ++ks) {
    bf16x8 a[4];
#pragma unroll
    for (int m = 0; m < 4; ++m) {
      if (ks < 4) {
        a[m] = cvt_frag(&accS[m * 16 + row][ks * 32 + quad * 8], invr[m]);
      } else {
        int e = e0 + m * 16 + row;
        a[m] = *(const bf16x8*)(attr_bf + (size_t)e * 64 + (ks - 4) * 32 + quad * 8);
      }
    }
#pragma unroll
    for (int m = 0; m < 4; ++m)
#pragma unroll
      for (int nl = 0; nl < 2; ++nl)
        acc[m][nl] = __builtin_amdgcn_mfma_f32_16x16x32_bf16(a[m], B1[nl][ks],
                                                             acc[m][nl], 0, 0, 0);
  }
  __syncthreads();   // all accS reads done before h1 overlay writes

#pragma unroll
  for (int nl = 0; nl < 2; ++nl) {
    float bias = b1[cb + nl * 16 + row];
#pragma unroll
    for (int m = 0; m < 4; ++m)
#pragma unroll
      for (int r = 0; r < 4; ++r)
        h1s[m * 16 + quad * 4 + r][cb + nl * 16 + row] =
            (short)f2bf(fmaxf(acc[m][nl][r] + bias, 0.0f));
  }

  bf16x8 B2[2][4];
#pragma unroll
  for (int nl = 0; nl < 2; ++nl)
#pragma unroll
    for (int ks = 0; ks < 4; ++ks)
      B2[nl][ks] = *(const bf16x8*)(w2 + (size_t)(cb + nl * 16 + row) * 128 +
                                    ks * 32 + quad * 8);
  __syncthreads();

  floatx4 acc2[4][2];
#pragma unroll
  for (int m = 0; m < 4; ++m)
#pragma unroll
    for (int nl = 0; nl < 2; ++nl) acc2[m][nl] = (floatx4){0.f, 0.f, 0.f, 0.f};

#pragma unroll
  for (int ks = 0; ks < 4; ++ks) {
    bf16x8 a[4];
#pragma unroll
    for (int m = 0; m < 4; ++m)
      a[m] = *(const bf16x8*)&h1s[m * 16 + row][ks * 32 + quad * 8];
#pragma unroll
    for (int m = 0; m < 4; ++m)
#pragma unroll
      for (int nl = 0; nl < 2; ++nl)
        acc2[m][nl] = __builtin_amdgcn_mfma_f32_16x16x32_bf16(a[m], B2[nl][ks],
                                                              acc2[m][nl], 0, 0, 0);
  }

#pragma unroll
  for (int nl = 0; nl < 2; ++nl) {
    int col = cb + nl * 16 + row;
    float bias = b2[col];
#pragma unroll
    for (int m = 0; m < 4; ++m)
#pragma unroll
      for (int r = 0; r < 4; ++r)
        edge_msg[(size_t)(e0 + m * 16 + quad * 4 + r) * 128 + col] =
            f2bf(acc2[m][nl][r] + bias);
  }
}

// ---------------------------------------------------------------------------
// Fused node: same gather structure on edge_msg rows + node MLP + LN.
// ---------------------------------------------------------------------------
__global__ __launch_bounds__(256, 4) void k_node_fused(
    const unsigned short* __restrict__ emsg, const short* __restrict__ xh_bf,
    const unsigned* __restrict__ pairs, const int* __restrict__ bcnt,
    const short* __restrict__ wp, const float* __restrict__ bp,
    const short* __restrict__ wn1, const float* __restrict__ bn1,
    const short* __restrict__ wn2, const float* __restrict__ bn2,
    const float* __restrict__ gamma, const float* __restrict__ beta,
    float* __restrict__ out) {
  __shared__ float accS[64][132];      // 33792 B; h1 overlay
  __shared__ unsigned raw[CAP_H];      // 4096 B; part[64][4] overlays
  __shared__ int cnts[64];
  short (*h1s)[136] = (short(*)[136])accS;
  float2 (*part)[4] = (float2(*)[4])raw;

  const int b = blockIdx.x;
  const int t = threadIdx.x;

  for (int i = t; i < 64 * 132; i += 256) ((float*)accS)[i] = 0.f;
  if (t < 64) cnts[t] = 0;

  int total = 0;
#pragma unroll
  for (int x = 0; x < 8; ++x) {
    int c = min(bcnt[((size_t)x * NBUCK_H + b) * BCNT_PAD], SUBCAP_H);
    const unsigned* src = pairs + ((size_t)x * NBUCK_H + b) * SUBCAP_H;
    for (int j = t; j < c; j += 256) {
      int d = total + j;
      if (d < CAP_H) raw[d] = src[j];
    }
    total += c;
  }
  const int cnt = min(total, CAP_H);
  __syncthreads();

  for (int j = t; j < cnt; j += 256)
    atomicAdd(&cnts[raw[j] >> 24], 1);

  const int wave = t >> 6, lane = t & 63;
  {
    const char* base = (const char*)emsg;
    int j = wave;
    for (; j + 12 < cnt; j += 16) {
      unsigned p0 = raw[j], p1 = raw[j + 4], p2 = raw[j + 8], p3 = raw[j + 12];
      unsigned v0 = *(const unsigned*)(base + ((size_t)(p0 & 0xFFFFFFu) << 8) + lane * 4);
      unsigned v1 = *(const unsigned*)(base + ((size_t)(p1 & 0xFFFFFFu) << 8) + lane * 4);
      unsigned v2 = *(const unsigned*)(base + ((size_t)(p2 & 0xFFFFFFu) << 8) + lane * 4);
      unsigned v3 = *(const unsigned*)(base + ((size_t)(p3 & 0xFFFFFFu) << 8) + lane * 4);
      int s0 = p0 >> 24, s1 = p1 >> 24, s2 = p2 >> 24, s3 = p3 >> 24;
      atomicAdd(&accS[s0][lane * 2],     bf2f((unsigned short)(v0 & 0xffffu)));
      atomicAdd(&accS[s0][lane * 2 + 1], bf2f((unsigned short)(v0 >> 16)));
      atomicAdd(&accS[s1][lane * 2],     bf2f((unsigned short)(v1 & 0xffffu)));
      atomicAdd(&accS[s1][lane * 2 + 1], bf2f((unsigned short)(v1 >> 16)));
      atomicAdd(&accS[s2][lane * 2],     bf2f((unsigned short)(v2 & 0xffffu)));
      atomicAdd(&accS[s2][lane * 2 + 1], bf2f((unsigned short)(v2 >> 16)));
      atomicAdd(&accS[s3][lane * 2],     bf2f((unsigned short)(v3 & 0xffffu)));
      atomicAdd(&accS[s3][lane * 2 + 1], bf2f((unsigned short)(v3 >> 16)));
    }
    for (; j < cnt; j += 4) {
      unsigned p0 = raw[j];
      unsigned v0 = *(const unsigned*)(base + ((size_t)(p0 & 0xFFFFFFu) << 8) + lane * 4);
      int s0 = p0 >> 24;
      atomicAdd(&accS[s0][lane * 2],     bf2f((unsigned short)(v0 & 0xffffu)));
      atomicAdd(&accS[s0][lane * 2 + 1], bf2f((unsigned short)(v0 >> 16)));
    }
  }
  __syncthreads();

  // ---- node MLP + LN ----
  const int row  = lane & 15;
  const int quad = lane >> 4;
  const int n0   = b * 64;
  const int cb   = wave * 32;

  float invr[4];
#pragma unroll
  for (int m = 0; m < 4; ++m) {
    int c = cnts[m * 16 + row];
    invr[m] = c > 0 ? 1.0f / (float)c : 0.0f;
  }

  bf16x8 B1[2][4];
#pragma unroll
  for (int nl = 0; nl < 2; ++nl)
#pragma unroll
    for (int ks = 0; ks < 4; ++ks)
      B1[nl][ks] = *(const bf16x8*)(wn1 + (size_t)(cb + nl * 16 + row) * 128 +
                                    ks * 32 + quad * 8);

  floatx4 acc[4][2];
#pragma unroll
  for (int m = 0; m < 4; ++m)
#pragma unroll
    for (int nl = 0; nl < 2; ++nl) acc[m][nl] = (floatx4){0.f, 0.f, 0.f, 0.f};

#pragma unroll
  for (int ks = 0; ks < 4; ++ks) {
    bf16x8 a[4];
#pragma unroll
    for (int m = 0; m < 4; ++m)
      a[m] = cvt_frag(&accS[m * 16 + row][ks * 32 + quad * 8], invr[m]);
#pragma unroll
    for (int m = 0; m < 4; ++m)
#pragma unroll
      for (int nl = 0; nl < 2; ++nl)
        acc[m][nl] = __builtin_amdgcn_mfma_f32_16x16x32_bf16(a[m], B1[nl][ks],
                                                             acc[m][nl], 0, 0, 0);
  }
  __syncthreads();   // all accS reads done before h1 overlay writes

#pragma unroll
  for (int nl = 0; nl < 2; ++nl) {
    float bias = bn1[cb + nl * 16 + row];
#pragma unroll
    for (int m = 0; m < 4; ++m)
#pragma unroll
      for (int r = 0; r < 4; ++r)
        h1s[m * 16 + quad * 4 + r][cb + nl * 16 + row] =
            (short)f2bf(fmaxf(acc[m][nl][r] + bias, 0.0f));
  }

  bf16x8 B2[2][4], Bp[2][4];
#pragma unroll
  for (int nl = 0; nl < 2; ++nl)
#pragma unroll
    for (int ks = 0; ks < 4; ++ks) {
      B2[nl][ks] = *(const bf16x8*)(wn2 + (size_t)(cb + nl * 16 + row) * 128 +
                                    ks * 32 + quad * 8);
      Bp[nl][ks] = *(const bf16x8*)(wp + (size_t)(cb + nl * 16 + row) * 128 +
                                    ks * 32 + quad * 8);
    }
  __syncthreads();

  floatx4 acc2[4][2];
#pragma unroll
  for (int m = 0; m < 4; ++m)
#pragma unroll
    for (int nl = 0; nl < 2; ++nl) acc2[m][nl] = (floatx4){0.f, 0.f, 0.f, 0.f};

#pragma unroll
  for (int ks = 0; ks < 4; ++ks) {
    bf16x8 at[4], ax[4];
#pragma unroll
    for (int m = 0; m < 4; ++m) {
      at[m] = *(const bf16x8*)&h1s[m * 16 + row][ks * 32 + quad * 8];
      int n = n0 + m * 16 + row;
      ax[m] = *(const bf16x8*)(xh_bf + (size_t)n * 128 + ks * 32 + quad * 8);
    }
#pragma unroll
    for (int m = 0; m < 4; ++m)
#pragma unroll
      for (int nl = 0; nl < 2; ++nl) {
        acc2[m][nl] = __builtin_amdgcn_mfma_f32_16x16x32_bf16(at[m], B2[nl][ks],
                                                              acc2[m][nl], 0, 0, 0);
        acc2[m][nl] = __builtin_amdgcn_mfma_f32_16x16x32_bf16(ax[m], Bp[nl][ks],
                                                              acc2[m][nl], 0, 0, 0);
      }
  }

  float z[4][2][4];
#pragma unroll
  for (int m = 0; m < 4; ++m) {
    float s[4], ss[4];
#pragma unroll
    for (int r = 0; r < 4; ++r) { s[r] = 0.f; ss[r] = 0.f; }
#pragma unroll
    for (int nl = 0; nl < 2; ++nl) {
      float bias = bp[cb + nl * 16 + row] + bn2[cb + nl * 16 + row];
#pragma unroll
      for (int r = 0; r < 4; ++r) {
        float v = fmaxf(acc2[m][nl][r] + bias, 0.0f);
        z[m][nl][r] = v;
        s[r] += v;
        ss[r] += v * v;
      }
    }
#pragma unroll
    for (int r = 0; r < 4; ++r) {
#pragma unroll
      for (int msk = 1; msk < 16; msk <<= 1) {
        s[r]  += __shfl_xor(s[r],  msk, 64);
        ss[r] += __shfl_xor(ss[r], msk, 64);
      }
      if (row == 0) part[m * 16 + quad * 4 + r][wave] = make_float2(s[r], ss[r]);
    }
  }
  __syncthreads();

#pragma unroll
  for (int m = 0; m < 4; ++m)
#pragma unroll
    for (int r = 0; r < 4; ++r) {
      int rr = m * 16 + quad * 4 + r;
      float2 p0 = part[rr][0], p1 = part[rr][1], p2 = part[rr][2], p3 = part[rr][3];
      float mean = (p0.x + p1.x + p2.x + p3.x) * (1.0f / 128.0f);
      float var  = (p0.y + p1.y + p2.y + p3.y) * (1.0f / 128.0f) - mean * mean;
      float rstd = rsqrtf(var + LN_EPS);
      int n = n0 + rr;
      if (n < H_N) {
#pragma unroll
        for (int nl = 0; nl < 2; ++nl) {
          int col = cb + nl * 16 + row;
          out[(size_t)n * 128 + col] =
              (z[m][nl][r] - mean) * rstd * gamma[col] + beta[col];
        }
      }
    }
}

// ---------------------------------------------------------------------------
extern "C" void kernel_launch(void* const* d_in, const int* in_sizes, int n_in,
                              void* d_out, int out_size, void* d_ws, size_t ws_size,
                              hipStream_t stream) {
  const float* x_h   = (const float*)d_in[0];
  const float* attr  = (const float*)d_in[1];
  const float* Wp    = (const float*)d_in[2];
  const float* bp    = (const float*)d_in[3];
  const float* We1   = (const float*)d_in[4];
  const float* be1   = (const float*)d_in[5];
  const float* We2   = (const float*)d_in[6];
  const float* be2   = (const float*)d_in[7];
  const float* Wn1   = (const float*)d_in[8];
  const float* bn1   = (const float*)d_in[9];
  const float* Wn2   = (const float*)d_in[10];
  const float* bn2   = (const float*)d_in[11];
  const float* gamma = (const float*)d_in[12];
  const float* beta  = (const float*)d_in[13];
  const int*   fg    = (const int*)d_in[14];
  const int*   res   = (const int*)d_in[15];
  float* out = (float*)d_out;

  // ---- workspace layout ----
  int* bcnt_e = (int*)d_ws;                                  // 8*NBUCK_E*16
  int* bcnt_h = bcnt_e + (size_t)8 * NBUCK_E * BCNT_PAD;     // 8*NBUCK_H*16
  unsigned* pairs_e = (unsigned*)(bcnt_h + (size_t)8 * NBUCK_H * BCNT_PAD);
  unsigned* pairs_h = pairs_e + (size_t)8 * NBUCK_E * SUBCAP_E;
  unsigned short* xh_bf    = (unsigned short*)(pairs_h + (size_t)8 * NBUCK_H * SUBCAP_H);
  unsigned short* edge_msg = xh_bf + (size_t)H_N * 128;
  short* w1  = (short*)(edge_msg + (size_t)E_N * 128);
  short* w2  = w1 + 128 * 192;
  short* wn1 = w2 + 128 * 128;
  short* wn2 = wn1 + 128 * 128;
  short* wp  = wn2 + 128 * 128;
  short* attr_bf = wp + 128 * 128;                           // E_N*64 bf16

  hipMemsetAsync(bcnt_e, 0,
                 (size_t)(8 * NBUCK_E + 8 * NBUCK_H) * BCNT_PAD * 4, stream);

  {
    int n4 = H_N * 128 / 4;
    k_cvt_bf16<<<(n4 + 255) / 256, 256, 0, stream>>>((const float4*)x_h, xh_bf, n4);
    n4 = E_N * 64 / 4;
    k_cvt_bf16<<<(n4 + 255) / 256, 256, 0, stream>>>((const float4*)attr, (unsigned short*)attr_bf, n4);
    n4 = 128 * 192 / 4;
    k_cvt_bf16<<<(n4 + 255) / 256, 256, 0, stream>>>((const float4*)We1, (unsigned short*)w1, n4);
    n4 = 128 * 128 / 4;
    k_cvt_bf16<<<(n4 + 255) / 256, 256, 0, stream>>>((const float4*)We2, (unsigned short*)w2, n4);
    k_cvt_bf16<<<(n4 + 255) / 256, 256, 0, stream>>>((const float4*)Wn1, (unsigned short*)wn1, n4);
    k_cvt_bf16<<<(n4 + 255) / 256, 256, 0, stream>>>((const float4*)Wn2, (unsigned short*)wn2, n4);
    k_cvt_bf16<<<(n4 + 255) / 256, 256, 0, stream>>>((const float4*)Wp, (unsigned short*)wp, n4);
  }

  k_bucket<<<(NI_N / 4 + 255) / 256, 256, 0, stream>>>(fg, res, bcnt_e, bcnt_h,
                                                       pairs_e, pairs_h);

  k_edge_fused<<<NBUCK_E, 256, 0, stream>>>(xh_bf, attr_bf, pairs_e, bcnt_e,
                                            w1, be1, w2, be2, edge_msg);
  k_node_fused<<<NBUCK_H, 256, 0, stream>>>(edge_msg, (const short*)xh_bf,
                                            pairs_h, bcnt_h,
                                            wp, bp, wn1, bn1, wn2, bn2,
                                            gamma, beta, out);
}

// Round 6
// 597.316 us; speedup vs baseline: 2.9115x; 2.9115x over previous
//
#include <hip/hip_runtime.h>

#define H_N   100000
#define E_N   200000
#define NI_N  1000000
#define LN_EPS 1e-5f

// Edge buckets: 64 edges each -> one MLP tile per bucket. 200000/64 = 3125 exactly.
#define NBUCK_E 3125
// Node buckets: 64 nodes each. ceil(100000/64) = 1563.
#define NBUCK_H 1563
#define SUBCAP_E 128       // per-XCD sub-bucket cap (mean 40, sigma ~6)
#define SUBCAP_H 192       // per-XCD sub-bucket cap (mean 80, sigma ~9)
#define CAP_E 512          // total per-bucket cap (mean 320, sigma ~18)
#define CAP_H 1024         // total per-bucket cap (mean 640, sigma ~25)
#define BCNT_PAD 16        // one counter per 64B line
#define GMASK 0x03FFFF00u  // byte-offset field of a sorted entry (bits 8..25)

typedef __attribute__((ext_vector_type(8))) short bf16x8;
typedef __attribute__((ext_vector_type(4))) float floatx4;
typedef __attribute__((ext_vector_type(4))) int intx4;

__device__ inline unsigned short f2bf(float f) {
  unsigned u = __builtin_bit_cast(unsigned, f);
  u += 0x7fffu + ((u >> 16) & 1u);           // round-to-nearest-even
  return (unsigned short)(u >> 16);
}
__device__ inline float bf2f(unsigned short s) {
  unsigned u = ((unsigned)s) << 16;
  return __builtin_bit_cast(float, u);
}
__device__ inline unsigned get_xcc() {
  unsigned x;
  asm volatile("s_getreg_b32 %0, hwreg(HW_REG_XCC_ID)" : "=s"(x));
  return x & 7;
}
// 8 consecutive f32 from LDS -> scaled bf16x8 fragment
__device__ inline bf16x8 cvt_frag(const float* p, float inv) {
  bf16x8 r;
#pragma unroll
  for (int i = 0; i < 8; ++i) r[i] = (short)f2bf(p[i] * inv);
  return r;
}

// ---------------------------------------------------------------------------
// fp32 -> bf16 conversion, 4 elements/thread
// ---------------------------------------------------------------------------
__global__ __launch_bounds__(256) void k_cvt_bf16(const float4* __restrict__ src,
                                                  unsigned short* __restrict__ dst,
                                                  int n4) {
  int i = blockIdx.x * 256 + threadIdx.x;
  if (i >= n4) return;
  float4 v = src[i];
  union { unsigned short us[4]; unsigned long long u64; } p;
  p.us[0] = f2bf(v.x); p.us[1] = f2bf(v.y);
  p.us[2] = f2bf(v.z); p.us[3] = f2bf(v.w);
  *(unsigned long long*)(dst + (size_t)i * 4) = p.u64;
}

// ---------------------------------------------------------------------------
// Bucket binning, XCD-local, 4 incidences/thread.
// ---------------------------------------------------------------------------
__global__ __launch_bounds__(256) void k_bucket(
    const int* __restrict__ fg, const int* __restrict__ res,
    int* __restrict__ bcnt_e, int* __restrict__ bcnt_h,
    unsigned* __restrict__ pairs_e, unsigned* __restrict__ pairs_h) {
  int i0 = (blockIdx.x * 256 + threadIdx.x) * 4;
  if (i0 >= NI_N) return;
  unsigned xcc = get_xcc();
  intx4 f4 = __builtin_nontemporal_load((const intx4*)(fg + i0));
  intx4 r4 = __builtin_nontemporal_load((const intx4*)(res + i0));
#pragma unroll
  for (int j = 0; j < 4; ++j) {
    int f = f4[j], r = r4[j];
    int be = r >> 6, se = r & 63;
    int pe = atomicAdd(bcnt_e + ((size_t)xcc * NBUCK_E + be) * BCNT_PAD, 1);
    if (pe < SUBCAP_E)
      pairs_e[((size_t)xcc * NBUCK_E + be) * SUBCAP_E + pe] =
          ((unsigned)se << 24) | (unsigned)f;
    int bh = f >> 6, sh = f & 63;
    int ph = atomicAdd(bcnt_h + ((size_t)xcc * NBUCK_H + bh) * BCNT_PAD, 1);
    if (ph < SUBCAP_H)
      pairs_h[((size_t)xcc * NBUCK_H + bh) * SUBCAP_H + ph] =
          ((unsigned)sh << 24) | (unsigned)r;
  }
}

// ---------------------------------------------------------------------------
// Sorted-run register-accumulate gather (shared by both fused kernels).
// Wave w owns sorted entries [w*cnt/4, (w+1)*cnt/4): all 64 lanes load the
// same entry's 256B row (lane = dword), accumulate in 2 VGPRs while the
// segment id stays constant; on boundary, flush via 2 ds_add_f32 per lane.
// Unroll-8: 8 independent row loads in flight per wave.
// sortedp entry = (seg << 26) | (row_idx << 8)  [byte offset of 256B row]
// ---------------------------------------------------------------------------
#define GATHER_RUNS(basePtr)                                                   \
  {                                                                            \
    const char* base = (const char*)(basePtr);                                 \
    int begin = (cnt * wave) >> 2;                                             \
    int end   = (cnt * (wave + 1)) >> 2;                                       \
    float a0 = 0.f, a1 = 0.f;                                                  \
    int cur = -1;                                                              \
    int j = begin;                                                             \
    for (; j + 7 < end; j += 8) {                                              \
      unsigned e[8]; unsigned v[8];                                            \
      _Pragma("unroll")                                                        \
      for (int u = 0; u < 8; ++u)                                              \
        e[u] = (unsigned)__builtin_amdgcn_readfirstlane((int)sortedp[j + u]);  \
      _Pragma("unroll")                                                        \
      for (int u = 0; u < 8; ++u)                                              \
        v[u] = *(const unsigned*)(base + (e[u] & GMASK) + lane * 4);           \
      _Pragma("unroll")                                                        \
      for (int u = 0; u < 8; ++u) {                                            \
        int s = (int)(e[u] >> 26);                                             \
        if (s != cur) {                                                        \
          if (cur >= 0) {                                                      \
            atomicAdd(&accS[cur][lane * 2], a0);                               \
            atomicAdd(&accS[cur][lane * 2 + 1], a1);                           \
          }                                                                    \
          cur = s; a0 = 0.f; a1 = 0.f;                                         \
        }                                                                      \
        a0 += bf2f((unsigned short)(v[u] & 0xffffu));                          \
        a1 += bf2f((unsigned short)(v[u] >> 16));                              \
      }                                                                        \
    }                                                                          \
    for (; j < end; ++j) {                                                     \
      unsigned e0 = (unsigned)__builtin_amdgcn_readfirstlane((int)sortedp[j]); \
      unsigned v0 = *(const unsigned*)(base + (e0 & GMASK) + lane * 4);        \
      int s = (int)(e0 >> 26);                                                 \
      if (s != cur) {                                                          \
        if (cur >= 0) {                                                        \
          atomicAdd(&accS[cur][lane * 2], a0);                                 \
          atomicAdd(&accS[cur][lane * 2 + 1], a1);                             \
        }                                                                      \
        cur = s; a0 = 0.f; a1 = 0.f;                                           \
      }                                                                        \
      a0 += bf2f((unsigned short)(v0 & 0xffffu));                              \
      a1 += bf2f((unsigned short)(v0 >> 16));                                  \
    }                                                                          \
    if (cur >= 0) {                                                            \
      atomicAdd(&accS[cur][lane * 2], a0);                                     \
      atomicAdd(&accS[cur][lane * 2 + 1], a1);                                 \
    }                                                                          \
  }

// ---------------------------------------------------------------------------
// Fused edge: concat -> counting sort -> sorted-run gather into f32 accS ->
// edge MLP (1/cnt + f32->bf16 folded into A-fragment load).
// accS doubles as h1 bf16 tile (barrier-separated). LDS ~38.4KB -> 4 blk/CU.
// ---------------------------------------------------------------------------
__global__ __launch_bounds__(256, 4) void k_edge_fused(
    const unsigned short* __restrict__ xh, const short* __restrict__ attr_bf,
    const unsigned* __restrict__ pairs, const int* __restrict__ bcnt,
    const short* __restrict__ w1, const float* __restrict__ b1,
    const short* __restrict__ w2, const float* __restrict__ b2,
    unsigned short* __restrict__ edge_msg) {
  __shared__ float accS[64][132];      // 33792 B; h1 bf16 tile overlays later
  __shared__ unsigned raw[CAP_E];      // 2048 B
  __shared__ unsigned sortedp[CAP_E];  // 2048 B
  __shared__ int cnts[65];
  __shared__ int curs[64];
  short (*h1s)[136] = (short(*)[136])accS;

  const int b = blockIdx.x;
  const int t = threadIdx.x;

  for (int i = t; i < 64 * 132; i += 256) ((float*)accS)[i] = 0.f;

  // ---- concat 8 per-XCD sub-lists ----
  int total = 0;
#pragma unroll
  for (int x = 0; x < 8; ++x) {
    int c = min(bcnt[((size_t)x * NBUCK_E + b) * BCNT_PAD], SUBCAP_E);
    const unsigned* src = pairs + ((size_t)x * NBUCK_E + b) * SUBCAP_E;
    for (int j = t; j < c; j += 256) {
      int d = total + j;
      if (d < CAP_E) raw[d] = src[j];
    }
    total += c;
  }
  const int cnt = min(total, CAP_E);
  if (t <= 64) cnts[t] = 0;
  __syncthreads();
  for (int j = t; j < cnt; j += 256)
    atomicAdd(&cnts[(raw[j] >> 24) + 1], 1);
  __syncthreads();
  for (int d = 1; d <= 64; d <<= 1) {
    int v = 0;
    if (t <= 64 && t >= d) v = cnts[t - d];
    __syncthreads();
    if (t <= 64) cnts[t] += v;
    __syncthreads();
  }
  if (t < 64) curs[t] = cnts[t];
  __syncthreads();
  for (int j = t; j < cnt; j += 256) {
    unsigned p = raw[j];
    int d = atomicAdd(&curs[p >> 24], 1);
    sortedp[d] = ((p >> 24) << 26) | ((p & 0xFFFFFFu) << 8);
  }
  __syncthreads();

  // ---- sorted-run gather-accumulate ----
  const int wave = t >> 6, lane = t & 63;
  GATHER_RUNS(xh);
  __syncthreads();

  // ---- edge MLP (A from accS f32, scaled+converted at load) ----
  const int row  = lane & 15;
  const int quad = lane >> 4;
  const int e0   = b * 64;
  const int cb   = wave * 32;

  float invr[4];
#pragma unroll
  for (int m = 0; m < 4; ++m) {
    int s = m * 16 + row;
    int c = cnts[s + 1] - cnts[s];
    invr[m] = c > 0 ? 1.0f / (float)c : 0.0f;
  }

  bf16x8 B1[2][6];
#pragma unroll
  for (int nl = 0; nl < 2; ++nl)
#pragma unroll
    for (int ks = 0; ks < 6; ++ks)
      B1[nl][ks] = *(const bf16x8*)(w1 + (size_t)(cb + nl * 16 + row) * 192 +
                                    ks * 32 + quad * 8);

  floatx4 acc[4][2];
#pragma unroll
  for (int m = 0; m < 4; ++m)
#pragma unroll
    for (int nl = 0; nl < 2; ++nl) acc[m][nl] = (floatx4){0.f, 0.f, 0.f, 0.f};

#pragma unroll
  for (int ks = 0; ks < 6; ++ks) {
    bf16x8 a[4];
#pragma unroll
    for (int m = 0; m < 4; ++m) {
      if (ks < 4) {
        a[m] = cvt_frag(&accS[m * 16 + row][ks * 32 + quad * 8], invr[m]);
      } else {
        int e = e0 + m * 16 + row;
        a[m] = *(const bf16x8*)(attr_bf + (size_t)e * 64 + (ks - 4) * 32 + quad * 8);
      }
    }
#pragma unroll
    for (int m = 0; m < 4; ++m)
#pragma unroll
      for (int nl = 0; nl < 2; ++nl)
        acc[m][nl] = __builtin_amdgcn_mfma_f32_16x16x32_bf16(a[m], B1[nl][ks],
                                                             acc[m][nl], 0, 0, 0);
  }
  __syncthreads();   // all accS reads done before h1 overlay writes

#pragma unroll
  for (int nl = 0; nl < 2; ++nl) {
    float bias = b1[cb + nl * 16 + row];
#pragma unroll
    for (int m = 0; m < 4; ++m)
#pragma unroll
      for (int r = 0; r < 4; ++r)
        h1s[m * 16 + quad * 4 + r][cb + nl * 16 + row] =
            (short)f2bf(fmaxf(acc[m][nl][r] + bias, 0.0f));
  }

  bf16x8 B2[2][4];
#pragma unroll
  for (int nl = 0; nl < 2; ++nl)
#pragma unroll
    for (int ks = 0; ks < 4; ++ks)
      B2[nl][ks] = *(const bf16x8*)(w2 + (size_t)(cb + nl * 16 + row) * 128 +
                                    ks * 32 + quad * 8);
  __syncthreads();

  floatx4 acc2[4][2];
#pragma unroll
  for (int m = 0; m < 4; ++m)
#pragma unroll
    for (int nl = 0; nl < 2; ++nl) acc2[m][nl] = (floatx4){0.f, 0.f, 0.f, 0.f};

#pragma unroll
  for (int ks = 0; ks < 4; ++ks) {
    bf16x8 a[4];
#pragma unroll
    for (int m = 0; m < 4; ++m)
      a[m] = *(const bf16x8*)&h1s[m * 16 + row][ks * 32 + quad * 8];
#pragma unroll
    for (int m = 0; m < 4; ++m)
#pragma unroll
      for (int nl = 0; nl < 2; ++nl)
        acc2[m][nl] = __builtin_amdgcn_mfma_f32_16x16x32_bf16(a[m], B2[nl][ks],
                                                              acc2[m][nl], 0, 0, 0);
  }

#pragma unroll
  for (int nl = 0; nl < 2; ++nl) {
    int col = cb + nl * 16 + row;
    float bias = b2[col];
#pragma unroll
    for (int m = 0; m < 4; ++m)
#pragma unroll
      for (int r = 0; r < 4; ++r)
        edge_msg[(size_t)(e0 + m * 16 + quad * 4 + r) * 128 + col] =
            f2bf(acc2[m][nl][r] + bias);
  }
}

// ---------------------------------------------------------------------------
// Fused node: same sorted-run gather on edge_msg rows + node MLP + LN.
// LDS ~42.5KB -> 3 blocks/CU.
// ---------------------------------------------------------------------------
__global__ __launch_bounds__(256, 3) void k_node_fused(
    const unsigned short* __restrict__ emsg, const short* __restrict__ xh_bf,
    const unsigned* __restrict__ pairs, const int* __restrict__ bcnt,
    const short* __restrict__ wp, const float* __restrict__ bp,
    const short* __restrict__ wn1, const float* __restrict__ bn1,
    const short* __restrict__ wn2, const float* __restrict__ bn2,
    const float* __restrict__ gamma, const float* __restrict__ beta,
    float* __restrict__ out) {
  __shared__ float accS[64][132];      // 33792 B; h1 overlay
  __shared__ unsigned raw[CAP_H];      // 4096 B; part[64][4] overlays
  __shared__ unsigned sortedp[CAP_H];  // 4096 B
  __shared__ int cnts[65];
  __shared__ int curs[64];
  short (*h1s)[136] = (short(*)[136])accS;
  float2 (*part)[4] = (float2(*)[4])raw;

  const int b = blockIdx.x;
  const int t = threadIdx.x;

  for (int i = t; i < 64 * 132; i += 256) ((float*)accS)[i] = 0.f;

  int total = 0;
#pragma unroll
  for (int x = 0; x < 8; ++x) {
    int c = min(bcnt[((size_t)x * NBUCK_H + b) * BCNT_PAD], SUBCAP_H);
    const unsigned* src = pairs + ((size_t)x * NBUCK_H + b) * SUBCAP_H;
    for (int j = t; j < c; j += 256) {
      int d = total + j;
      if (d < CAP_H) raw[d] = src[j];
    }
    total += c;
  }
  const int cnt = min(total, CAP_H);
  if (t <= 64) cnts[t] = 0;
  __syncthreads();
  for (int j = t; j < cnt; j += 256)
    atomicAdd(&cnts[(raw[j] >> 24) + 1], 1);
  __syncthreads();
  for (int d = 1; d <= 64; d <<= 1) {
    int v = 0;
    if (t <= 64 && t >= d) v = cnts[t - d];
    __syncthreads();
    if (t <= 64) cnts[t] += v;
    __syncthreads();
  }
  if (t < 64) curs[t] = cnts[t];
  __syncthreads();
  for (int j = t; j < cnt; j += 256) {
    unsigned p = raw[j];
    int d = atomicAdd(&curs[p >> 24], 1);
    sortedp[d] = ((p >> 24) << 26) | ((p & 0xFFFFFFu) << 8);
  }
  __syncthreads();

  const int wave = t >> 6, lane = t & 63;
  GATHER_RUNS(emsg);
  __syncthreads();

  // ---- node MLP + LN ----
  const int row  = lane & 15;
  const int quad = lane >> 4;
  const int n0   = b * 64;
  const int cb   = wave * 32;

  float invr[4];
#pragma unroll
  for (int m = 0; m < 4; ++m) {
    int s = m * 16 + row;
    int c = cnts[s + 1] - cnts[s];
    invr[m] = c > 0 ? 1.0f / (float)c : 0.0f;
  }

  bf16x8 B1[2][4];
#pragma unroll
  for (int nl = 0; nl < 2; ++nl)
#pragma unroll
    for (int ks = 0; ks < 4; ++ks)
      B1[nl][ks] = *(const bf16x8*)(wn1 + (size_t)(cb + nl * 16 + row) * 128 +
                                    ks * 32 + quad * 8);

  floatx4 acc[4][2];
#pragma unroll
  for (int m = 0; m < 4; ++m)
#pragma unroll
    for (int nl = 0; nl < 2; ++nl) acc[m][nl] = (floatx4){0.f, 0.f, 0.f, 0.f};

#pragma unroll
  for (int ks = 0; ks < 4; ++ks) {
    bf16x8 a[4];
#pragma unroll
    for (int m = 0; m < 4; ++m)
      a[m] = cvt_frag(&accS[m * 16 + row][ks * 32 + quad * 8], invr[m]);
#pragma unroll
    for (int m = 0; m < 4; ++m)
#pragma unroll
      for (int nl = 0; nl < 2; ++nl)
        acc[m][nl] = __builtin_amdgcn_mfma_f32_16x16x32_bf16(a[m], B1[nl][ks],
                                                             acc[m][nl], 0, 0, 0);
  }
  __syncthreads();   // all accS reads done before h1 overlay writes

#pragma unroll
  for (int nl = 0; nl < 2; ++nl) {
    float bias = bn1[cb + nl * 16 + row];
#pragma unroll
    for (int m = 0; m < 4; ++m)
#pragma unroll
      for (int r = 0; r < 4; ++r)
        h1s[m * 16 + quad * 4 + r][cb + nl * 16 + row] =
            (short)f2bf(fmaxf(acc[m][nl][r] + bias, 0.0f));
  }

  bf16x8 B2[2][4], Bp[2][4];
#pragma unroll
  for (int nl = 0; nl < 2; ++nl)
#pragma unroll
    for (int ks = 0; ks < 4; ++ks) {
      B2[nl][ks] = *(const bf16x8*)(wn2 + (size_t)(cb + nl * 16 + row) * 128 +
                                    ks * 32 + quad * 8);
      Bp[nl][ks] = *(const bf16x8*)(wp + (size_t)(cb + nl * 16 + row) * 128 +
                                    ks * 32 + quad * 8);
    }
  __syncthreads();

  floatx4 acc2[4][2];
#pragma unroll
  for (int m = 0; m < 4; ++m)
#pragma unroll
    for (int nl = 0; nl < 2; ++nl) acc2[m][nl] = (floatx4){0.f, 0.f, 0.f, 0.f};

#pragma unroll
  for (int ks = 0; ks < 4; ++ks) {
    bf16x8 at[4], ax[4];
#pragma unroll
    for (int m = 0; m < 4; ++m) {
      at[m] = *(const bf16x8*)&h1s[m * 16 + row][ks * 32 + quad * 8];
      int n = n0 + m * 16 + row;
      ax[m] = *(const bf16x8*)(xh_bf + (size_t)n * 128 + ks * 32 + quad * 8);
    }
#pragma unroll
    for (int m = 0; m < 4; ++m)
#pragma unroll
      for (int nl = 0; nl < 2; ++nl) {
        acc2[m][nl] = __builtin_amdgcn_mfma_f32_16x16x32_bf16(at[m], B2[nl][ks],
                                                              acc2[m][nl], 0, 0, 0);
        acc2[m][nl] = __builtin_amdgcn_mfma_f32_16x16x32_bf16(ax[m], Bp[nl][ks],
                                                              acc2[m][nl], 0, 0, 0);
      }
  }

  float z[4][2][4];
#pragma unroll
  for (int m = 0; m < 4; ++m) {
    float s[4], ss[4];
#pragma unroll
    for (int r = 0; r < 4; ++r) { s[r] = 0.f; ss[r] = 0.f; }
#pragma unroll
    for (int nl = 0; nl < 2; ++nl) {
      float bias = bp[cb + nl * 16 + row] + bn2[cb + nl * 16 + row];
#pragma unroll
      for (int r = 0; r < 4; ++r) {
        float v = fmaxf(acc2[m][nl][r] + bias, 0.0f);
        z[m][nl][r] = v;
        s[r] += v;
        ss[r] += v * v;
      }
    }
#pragma unroll
    for (int r = 0; r < 4; ++r) {
#pragma unroll
      for (int msk = 1; msk < 16; msk <<= 1) {
        s[r]  += __shfl_xor(s[r],  msk, 64);
        ss[r] += __shfl_xor(ss[r], msk, 64);
      }
      if (row == 0) part[m * 16 + quad * 4 + r][wave] = make_float2(s[r], ss[r]);
    }
  }
  __syncthreads();

#pragma unroll
  for (int m = 0; m < 4; ++m)
#pragma unroll
    for (int r = 0; r < 4; ++r) {
      int rr = m * 16 + quad * 4 + r;
      float2 p0 = part[rr][0], p1 = part[rr][1], p2 = part[rr][2], p3 = part[rr][3];
      float mean = (p0.x + p1.x + p2.x + p3.x) * (1.0f / 128.0f);
      float var  = (p0.y + p1.y + p2.y + p3.y) * (1.0f / 128.0f) - mean * mean;
      float rstd = rsqrtf(var + LN_EPS);
      int n = n0 + rr;
      if (n < H_N) {
#pragma unroll
        for (int nl = 0; nl < 2; ++nl) {
          int col = cb + nl * 16 + row;
          out[(size_t)n * 128 + col] =
              (z[m][nl][r] - mean) * rstd * gamma[col] + beta[col];
        }
      }
    }
}

// ---------------------------------------------------------------------------
extern "C" void kernel_launch(void* const* d_in, const int* in_sizes, int n_in,
                              void* d_out, int out_size, void* d_ws, size_t ws_size,
                              hipStream_t stream) {
  const float* x_h   = (const float*)d_in[0];
  const float* attr  = (const float*)d_in[1];
  const float* Wp    = (const float*)d_in[2];
  const float* bp    = (const float*)d_in[3];
  const float* We1   = (const float*)d_in[4];
  const float* be1   = (const float*)d_in[5];
  const float* We2   = (const float*)d_in[6];
  const float* be2   = (const float*)d_in[7];
  const float* Wn1   = (const float*)d_in[8];
  const float* bn1   = (const float*)d_in[9];
  const float* Wn2   = (const float*)d_in[10];
  const float* bn2   = (const float*)d_in[11];
  const float* gamma = (const float*)d_in[12];
  const float* beta  = (const float*)d_in[13];
  const int*   fg    = (const int*)d_in[14];
  const int*   res   = (const int*)d_in[15];
  float* out = (float*)d_out;

  // ---- workspace layout ----
  int* bcnt_e = (int*)d_ws;                                  // 8*NBUCK_E*16
  int* bcnt_h = bcnt_e + (size_t)8 * NBUCK_E * BCNT_PAD;     // 8*NBUCK_H*16
  unsigned* pairs_e = (unsigned*)(bcnt_h + (size_t)8 * NBUCK_H * BCNT_PAD);
  unsigned* pairs_h = pairs_e + (size_t)8 * NBUCK_E * SUBCAP_E;
  unsigned short* xh_bf    = (unsigned short*)(pairs_h + (size_t)8 * NBUCK_H * SUBCAP_H);
  unsigned short* edge_msg = xh_bf + (size_t)H_N * 128;
  short* w1  = (short*)(edge_msg + (size_t)E_N * 128);
  short* w2  = w1 + 128 * 192;
  short* wn1 = w2 + 128 * 128;
  short* wn2 = wn1 + 128 * 128;
  short* wp  = wn2 + 128 * 128;
  short* attr_bf = wp + 128 * 128;                           // E_N*64 bf16

  hipMemsetAsync(bcnt_e, 0,
                 (size_t)(8 * NBUCK_E + 8 * NBUCK_H) * BCNT_PAD * 4, stream);

  {
    int n4 = H_N * 128 / 4;
    k_cvt_bf16<<<(n4 + 255) / 256, 256, 0, stream>>>((const float4*)x_h, xh_bf, n4);
    n4 = E_N * 64 / 4;
    k_cvt_bf16<<<(n4 + 255) / 256, 256, 0, stream>>>((const float4*)attr, (unsigned short*)attr_bf, n4);
    n4 = 128 * 192 / 4;
    k_cvt_bf16<<<(n4 + 255) / 256, 256, 0, stream>>>((const float4*)We1, (unsigned short*)w1, n4);
    n4 = 128 * 128 / 4;
    k_cvt_bf16<<<(n4 + 255) / 256, 256, 0, stream>>>((const float4*)We2, (unsigned short*)w2, n4);
    k_cvt_bf16<<<(n4 + 255) / 256, 256, 0, stream>>>((const float4*)Wn1, (unsigned short*)wn1, n4);
    k_cvt_bf16<<<(n4 + 255) / 256, 256, 0, stream>>>((const float4*)Wn2, (unsigned short*)wn2, n4);
    k_cvt_bf16<<<(n4 + 255) / 256, 256, 0, stream>>>((const float4*)Wp, (unsigned short*)wp, n4);
  }

  k_bucket<<<(NI_N / 4 + 255) / 256, 256, 0, stream>>>(fg, res, bcnt_e, bcnt_h,
                                                       pairs_e, pairs_h);

  k_edge_fused<<<NBUCK_E, 256, 0, stream>>>(xh_bf, attr_bf, pairs_e, bcnt_e,
                                            w1, be1, w2, be2, edge_msg);
  k_node_fused<<<NBUCK_H, 256, 0, stream>>>(edge_msg, (const short*)xh_bf,
                                            pairs_h, bcnt_h,
                                            wp, bp, wn1, bn1, wn2, bn2,
                                            gamma, beta, out);
}

// Round 7
// 476.179 us; speedup vs baseline: 3.6521x; 1.2544x over previous
//
#include <hip/hip_runtime.h>

#define H_N   100000
#define E_N   200000
#define NI_N  1000000
#define LN_EPS 1e-5f

// Edge buckets: 64 edges each -> one MLP tile per bucket. 200000/64 = 3125 exactly.
#define NBUCK_E 3125
// Node buckets: 64 nodes each. ceil(100000/64) = 1563.
#define NBUCK_H 1563
#define SUBCAP_E 128       // per-XCD sub-bucket cap (mean 40, sigma ~6)
#define SUBCAP_H 192       // per-XCD sub-bucket cap (mean 80, sigma ~9)
#define CAP_E 512          // total per-bucket cap (mean 320, sigma ~18)
#define CAP_H 1024         // total per-bucket cap (mean 640, sigma ~25)
#define BCNT_PAD 16        // one counter per 64B line: kills same-line atomic RMW serialization

typedef __attribute__((ext_vector_type(8))) short bf16x8;
typedef __attribute__((ext_vector_type(4))) float floatx4;
typedef __attribute__((ext_vector_type(4))) int intx4;
typedef __attribute__((ext_vector_type(4))) unsigned uintx4;

__device__ inline unsigned short f2bf(float f) {
  unsigned u = __builtin_bit_cast(unsigned, f);
  u += 0x7fffu + ((u >> 16) & 1u);           // round-to-nearest-even
  return (unsigned short)(u >> 16);
}
__device__ inline float bf2f(unsigned short s) {
  unsigned u = ((unsigned)s) << 16;
  return __builtin_bit_cast(float, u);
}
__device__ inline unsigned get_xcc() {
  unsigned x;
  asm volatile("s_getreg_b32 %0, hwreg(HW_REG_XCC_ID)" : "=s"(x));
  return x & 7;
}

// ---------------------------------------------------------------------------
// fp32 -> bf16 conversion, 4 elements/thread
// ---------------------------------------------------------------------------
__global__ __launch_bounds__(256) void k_cvt_bf16(const float4* __restrict__ src,
                                                  unsigned short* __restrict__ dst,
                                                  int n4) {
  int i = blockIdx.x * 256 + threadIdx.x;
  if (i >= n4) return;
  float4 v = src[i];
  union { unsigned short us[4]; unsigned long long u64; } p;
  p.us[0] = f2bf(v.x); p.us[1] = f2bf(v.y);
  p.us[2] = f2bf(v.z); p.us[3] = f2bf(v.w);
  *(unsigned long long*)(dst + (size_t)i * 4) = p.u64;
}

// ---------------------------------------------------------------------------
// Bucket binning, XCD-local, 4 incidences/thread.
// ---------------------------------------------------------------------------
__global__ __launch_bounds__(256) void k_bucket(
    const int* __restrict__ fg, const int* __restrict__ res,
    int* __restrict__ bcnt_e, int* __restrict__ bcnt_h,
    unsigned* __restrict__ pairs_e, unsigned* __restrict__ pairs_h) {
  int i0 = (blockIdx.x * 256 + threadIdx.x) * 4;
  if (i0 >= NI_N) return;
  unsigned xcc = get_xcc();
  intx4 f4 = __builtin_nontemporal_load((const intx4*)(fg + i0));
  intx4 r4 = __builtin_nontemporal_load((const intx4*)(res + i0));
#pragma unroll
  for (int j = 0; j < 4; ++j) {
    int f = f4[j], r = r4[j];
    int be = r >> 6, se = r & 63;
    int pe = atomicAdd(bcnt_e + ((size_t)xcc * NBUCK_E + be) * BCNT_PAD, 1);
    if (pe < SUBCAP_E)
      pairs_e[((size_t)xcc * NBUCK_E + be) * SUBCAP_E + pe] =
          ((unsigned)se << 24) | (unsigned)f;
    int bh = f >> 6, sh = f & 63;
    int ph = atomicAdd(bcnt_h + ((size_t)xcc * NBUCK_H + bh) * BCNT_PAD, 1);
    if (ph < SUBCAP_H)
      pairs_h[((size_t)xcc * NBUCK_H + bh) * SUBCAP_H + ph] =
          ((unsigned)sh << 24) | (unsigned)r;
  }
}

// ---------------------------------------------------------------------------
// Quarter-wave gather: 16 lanes x 16B = one full 256B row per load instr.
// The wave's 4 quarters take entries j==q (mod 4) of the segment, unroll 2
// -> up to 8 independent row loads in flight per wave. 8 f32 accumulators
// per lane; cross-quarter reduce = 2 shfl_xor; quarter 0 writes the bf16
// mean (16B store) to meanS[s].
// ---------------------------------------------------------------------------
#define GATHER_QW(basePtr)                                                     \
  for (int s = wave; s < 64; s += 4) {                                         \
    int o = cnts[s], e = cnts[s + 1];                                          \
    float a[8];                                                                \
    _Pragma("unroll")                                                          \
    for (int k = 0; k < 8; ++k) a[k] = 0.f;                                    \
    int j = o + q;                                                             \
    for (; j + 4 < e; j += 8) {                                                \
      unsigned off0 = sortedp[j], off1 = sortedp[j + 4];                       \
      uintx4 v0 = *(const uintx4*)((const char*)(basePtr) + off0 + ql * 16);   \
      uintx4 v1 = *(const uintx4*)((const char*)(basePtr) + off1 + ql * 16);   \
      _Pragma("unroll")                                                        \
      for (int k = 0; k < 4; ++k) {                                            \
        a[2 * k]     += bf2f((unsigned short)(v0[k] & 0xffffu)) +              \
                        bf2f((unsigned short)(v1[k] & 0xffffu));               \
        a[2 * k + 1] += bf2f((unsigned short)(v0[k] >> 16)) +                  \
                        bf2f((unsigned short)(v1[k] >> 16));                   \
      }                                                                        \
    }                                                                          \
    if (j < e) {                                                               \
      unsigned off0 = sortedp[j];                                              \
      uintx4 v0 = *(const uintx4*)((const char*)(basePtr) + off0 + ql * 16);   \
      _Pragma("unroll")                                                        \
      for (int k = 0; k < 4; ++k) {                                            \
        a[2 * k]     += bf2f((unsigned short)(v0[k] & 0xffffu));               \
        a[2 * k + 1] += bf2f((unsigned short)(v0[k] >> 16));                   \
      }                                                                        \
    }                                                                          \
    _Pragma("unroll")                                                          \
    for (int k = 0; k < 8; ++k) {                                              \
      a[k] += __shfl_xor(a[k], 16, 64);                                        \
      a[k] += __shfl_xor(a[k], 32, 64);                                        \
    }                                                                          \
    if (q == 0) {                                                              \
      float inv = (e > o) ? 1.0f / (float)(e - o) : 0.0f;                      \
      uintx4 ov;                                                               \
      _Pragma("unroll")                                                        \
      for (int k = 0; k < 4; ++k)                                              \
        ov[k] = (unsigned)f2bf(a[2 * k] * inv) |                               \
                ((unsigned)f2bf(a[2 * k + 1] * inv) << 16);                    \
      *(uintx4*)&meanS[s][ql * 8] = ov;                                        \
    }                                                                          \
  }

// ---------------------------------------------------------------------------
// Fused edge: concat -> counting sort -> quarter-wave gather-mean (LDS bf16)
// -> edge MLP. h1 overlays meanS (barrier-separated). LDS ~22KB, 6 blk/CU.
// ---------------------------------------------------------------------------
__global__ __launch_bounds__(256, 6) void k_edge_fused(
    const unsigned short* __restrict__ xh, const short* __restrict__ attr_bf,
    const unsigned* __restrict__ pairs, const int* __restrict__ bcnt,
    const short* __restrict__ w1, const float* __restrict__ b1,
    const short* __restrict__ w2, const float* __restrict__ b2,
    unsigned short* __restrict__ edge_msg) {
  __shared__ short meanS[64][136];     // 17408 B; doubles as h1 after barrier
  __shared__ unsigned raw[CAP_E];      // 2048
  __shared__ unsigned sortedp[CAP_E];  // 2048
  __shared__ int cnts[65];
  __shared__ int curs[64];
  short (*h1s)[136] = meanS;

  const int b = blockIdx.x;
  const int t = threadIdx.x;

  // ---- concat 8 per-XCD sub-lists ----
  int total = 0;
#pragma unroll
  for (int x = 0; x < 8; ++x) {
    int c = min(bcnt[((size_t)x * NBUCK_E + b) * BCNT_PAD], SUBCAP_E);
    const unsigned* src = pairs + ((size_t)x * NBUCK_E + b) * SUBCAP_E;
    for (int j = t; j < c; j += 256) {
      int d = total + j;
      if (d < CAP_E) raw[d] = src[j];
    }
    total += c;
  }
  const int cnt = min(total, CAP_E);
  if (t <= 64) cnts[t] = 0;
  __syncthreads();
  for (int j = t; j < cnt; j += 256)
    atomicAdd(&cnts[(raw[j] >> 24) + 1], 1);
  __syncthreads();
  for (int d = 1; d <= 64; d <<= 1) {
    int v = 0;
    if (t <= 64 && t >= d) v = cnts[t - d];
    __syncthreads();
    if (t <= 64) cnts[t] += v;
    __syncthreads();
  }
  if (t < 64) curs[t] = cnts[t];
  __syncthreads();
  for (int j = t; j < cnt; j += 256) {
    unsigned p = raw[j];
    int d = atomicAdd(&curs[p >> 24], 1);
    sortedp[d] = (p & 0xFFFFFFu) << 8;   // byte offset of 256B row
  }
  __syncthreads();

  // ---- quarter-wave gather-mean into LDS tile ----
  const int wave = t >> 6, lane = t & 63;
  const int q = lane >> 4, ql = lane & 15;
  GATHER_QW(xh);
  __syncthreads();

  // ---- edge MLP (A from LDS) ----
  const int row  = lane & 15;
  const int quad = lane >> 4;
  const int e0   = b * 64;
  const int cb   = wave * 32;

  bf16x8 B1[2][6];
#pragma unroll
  for (int nl = 0; nl < 2; ++nl)
#pragma unroll
    for (int ks = 0; ks < 6; ++ks)
      B1[nl][ks] = *(const bf16x8*)(w1 + (size_t)(cb + nl * 16 + row) * 192 +
                                    ks * 32 + quad * 8);

  floatx4 acc[4][2];
#pragma unroll
  for (int m = 0; m < 4; ++m)
#pragma unroll
    for (int nl = 0; nl < 2; ++nl) acc[m][nl] = (floatx4){0.f, 0.f, 0.f, 0.f};

#pragma unroll
  for (int ks = 0; ks < 6; ++ks) {
    bf16x8 a[4];
#pragma unroll
    for (int m = 0; m < 4; ++m) {
      if (ks < 4) {
        a[m] = *(const bf16x8*)&meanS[m * 16 + row][ks * 32 + quad * 8];
      } else {
        int e = e0 + m * 16 + row;
        a[m] = *(const bf16x8*)(attr_bf + (size_t)e * 64 + (ks - 4) * 32 + quad * 8);
      }
    }
#pragma unroll
    for (int m = 0; m < 4; ++m)
#pragma unroll
      for (int nl = 0; nl < 2; ++nl)
        acc[m][nl] = __builtin_amdgcn_mfma_f32_16x16x32_bf16(a[m], B1[nl][ks],
                                                             acc[m][nl], 0, 0, 0);
  }
  __syncthreads();   // all meanS reads done before h1 overlay writes

#pragma unroll
  for (int nl = 0; nl < 2; ++nl) {
    float bias = b1[cb + nl * 16 + row];
#pragma unroll
    for (int m = 0; m < 4; ++m)
#pragma unroll
      for (int r = 0; r < 4; ++r)
        h1s[m * 16 + quad * 4 + r][cb + nl * 16 + row] =
            (short)f2bf(fmaxf(acc[m][nl][r] + bias, 0.0f));
  }

  bf16x8 B2[2][4];
#pragma unroll
  for (int nl = 0; nl < 2; ++nl)
#pragma unroll
    for (int ks = 0; ks < 4; ++ks)
      B2[nl][ks] = *(const bf16x8*)(w2 + (size_t)(cb + nl * 16 + row) * 128 +
                                    ks * 32 + quad * 8);
  __syncthreads();

  floatx4 acc2[4][2];
#pragma unroll
  for (int m = 0; m < 4; ++m)
#pragma unroll
    for (int nl = 0; nl < 2; ++nl) acc2[m][nl] = (floatx4){0.f, 0.f, 0.f, 0.f};

#pragma unroll
  for (int ks = 0; ks < 4; ++ks) {
    bf16x8 a[4];
#pragma unroll
    for (int m = 0; m < 4; ++m)
      a[m] = *(const bf16x8*)&h1s[m * 16 + row][ks * 32 + quad * 8];
#pragma unroll
    for (int m = 0; m < 4; ++m)
#pragma unroll
      for (int nl = 0; nl < 2; ++nl)
        acc2[m][nl] = __builtin_amdgcn_mfma_f32_16x16x32_bf16(a[m], B2[nl][ks],
                                                              acc2[m][nl], 0, 0, 0);
  }

#pragma unroll
  for (int nl = 0; nl < 2; ++nl) {
    int col = cb + nl * 16 + row;
    float bias = b2[col];
#pragma unroll
    for (int m = 0; m < 4; ++m)
#pragma unroll
      for (int r = 0; r < 4; ++r)
        edge_msg[(size_t)(e0 + m * 16 + quad * 4 + r) * 128 + col] =
            f2bf(acc2[m][nl][r] + bias);
  }
}

// ---------------------------------------------------------------------------
// Fused node: quarter-wave gather on edge_msg rows + node MLP + LN.
// LDS ~26.1KB -> 5 blocks/CU: h1 overlays meanS, part overlays raw.
// ---------------------------------------------------------------------------
__global__ __launch_bounds__(256, 5) void k_node_fused(
    const unsigned short* __restrict__ emsg, const short* __restrict__ xh_bf,
    const unsigned* __restrict__ pairs, const int* __restrict__ bcnt,
    const short* __restrict__ wp, const float* __restrict__ bp,
    const short* __restrict__ wn1, const float* __restrict__ bn1,
    const short* __restrict__ wn2, const float* __restrict__ bn2,
    const float* __restrict__ gamma, const float* __restrict__ beta,
    float* __restrict__ out) {
  __shared__ short meanS[64][136];     // 17408 B; doubles as h1
  __shared__ unsigned raw[CAP_H];      // 4096 B; doubles as part[64][4] (2048 B)
  __shared__ unsigned sortedp[CAP_H];  // 4096
  __shared__ int cnts[65];
  __shared__ int curs[64];
  short (*h1s)[136] = meanS;
  float2 (*part)[4] = (float2(*)[4])raw;

  const int b = blockIdx.x;
  const int t = threadIdx.x;

  int total = 0;
#pragma unroll
  for (int x = 0; x < 8; ++x) {
    int c = min(bcnt[((size_t)x * NBUCK_H + b) * BCNT_PAD], SUBCAP_H);
    const unsigned* src = pairs + ((size_t)x * NBUCK_H + b) * SUBCAP_H;
    for (int j = t; j < c; j += 256) {
      int d = total + j;
      if (d < CAP_H) raw[d] = src[j];
    }
    total += c;
  }
  const int cnt = min(total, CAP_H);
  if (t <= 64) cnts[t] = 0;
  __syncthreads();
  for (int j = t; j < cnt; j += 256)
    atomicAdd(&cnts[(raw[j] >> 24) + 1], 1);
  __syncthreads();
  for (int d = 1; d <= 64; d <<= 1) {
    int v = 0;
    if (t <= 64 && t >= d) v = cnts[t - d];
    __syncthreads();
    if (t <= 64) cnts[t] += v;
    __syncthreads();
  }
  if (t < 64) curs[t] = cnts[t];
  __syncthreads();
  for (int j = t; j < cnt; j += 256) {
    unsigned p = raw[j];
    int d = atomicAdd(&curs[p >> 24], 1);
    sortedp[d] = (p & 0xFFFFFFu) << 8;   // byte offset of 256B row
  }
  __syncthreads();

  const int wave = t >> 6, lane = t & 63;
  const int q = lane >> 4, ql = lane & 15;
  const int segs_here = min(64, H_N - b * 64);
  // zero the tail segments' rows (beyond segs_here the cnts are all zero
  // anyway, so GATHER_QW writes zeros; no special-case needed since
  // cnts[s]==cnts[s+1] for empty segments and inv=0)
  GATHER_QW(emsg);
  (void)segs_here;
  __syncthreads();

  // ---- node MLP + LN (A from LDS) ----
  const int row  = lane & 15;
  const int quad = lane >> 4;
  const int n0   = b * 64;
  const int cb   = wave * 32;

  bf16x8 B1[2][4];
#pragma unroll
  for (int nl = 0; nl < 2; ++nl)
#pragma unroll
    for (int ks = 0; ks < 4; ++ks)
      B1[nl][ks] = *(const bf16x8*)(wn1 + (size_t)(cb + nl * 16 + row) * 128 +
                                    ks * 32 + quad * 8);

  floatx4 acc[4][2];
#pragma unroll
  for (int m = 0; m < 4; ++m)
#pragma unroll
    for (int nl = 0; nl < 2; ++nl) acc[m][nl] = (floatx4){0.f, 0.f, 0.f, 0.f};

#pragma unroll
  for (int ks = 0; ks < 4; ++ks) {
    bf16x8 a[4];
#pragma unroll
    for (int m = 0; m < 4; ++m)
      a[m] = *(const bf16x8*)&meanS[m * 16 + row][ks * 32 + quad * 8];
#pragma unroll
    for (int m = 0; m < 4; ++m)
#pragma unroll
      for (int nl = 0; nl < 2; ++nl)
        acc[m][nl] = __builtin_amdgcn_mfma_f32_16x16x32_bf16(a[m], B1[nl][ks],
                                                             acc[m][nl], 0, 0, 0);
  }
  __syncthreads();   // all meanS reads done before h1 overlay writes

#pragma unroll
  for (int nl = 0; nl < 2; ++nl) {
    float bias = bn1[cb + nl * 16 + row];
#pragma unroll
    for (int m = 0; m < 4; ++m)
#pragma unroll
      for (int r = 0; r < 4; ++r)
        h1s[m * 16 + quad * 4 + r][cb + nl * 16 + row] =
            (short)f2bf(fmaxf(acc[m][nl][r] + bias, 0.0f));
  }

  bf16x8 B2[2][4], Bp[2][4];
#pragma unroll
  for (int nl = 0; nl < 2; ++nl)
#pragma unroll
    for (int ks = 0; ks < 4; ++ks) {
      B2[nl][ks] = *(const bf16x8*)(wn2 + (size_t)(cb + nl * 16 + row) * 128 +
                                    ks * 32 + quad * 8);
      Bp[nl][ks] = *(const bf16x8*)(wp + (size_t)(cb + nl * 16 + row) * 128 +
                                    ks * 32 + quad * 8);
    }
  __syncthreads();

  floatx4 acc2[4][2];
#pragma unroll
  for (int m = 0; m < 4; ++m)
#pragma unroll
    for (int nl = 0; nl < 2; ++nl) acc2[m][nl] = (floatx4){0.f, 0.f, 0.f, 0.f};

#pragma unroll
  for (int ks = 0; ks < 4; ++ks) {
    bf16x8 at[4], ax[4];
#pragma unroll
    for (int m = 0; m < 4; ++m) {
      at[m] = *(const bf16x8*)&h1s[m * 16 + row][ks * 32 + quad * 8];
      int n = n0 + m * 16 + row;
      ax[m] = *(const bf16x8*)(xh_bf + (size_t)n * 128 + ks * 32 + quad * 8);
    }
#pragma unroll
    for (int m = 0; m < 4; ++m)
#pragma unroll
      for (int nl = 0; nl < 2; ++nl) {
        acc2[m][nl] = __builtin_amdgcn_mfma_f32_16x16x32_bf16(at[m], B2[nl][ks],
                                                              acc2[m][nl], 0, 0, 0);
        acc2[m][nl] = __builtin_amdgcn_mfma_f32_16x16x32_bf16(ax[m], Bp[nl][ks],
                                                              acc2[m][nl], 0, 0, 0);
      }
  }

  float z[4][2][4];
#pragma unroll
  for (int m = 0; m < 4; ++m) {
    float s[4], ss[4];
#pragma unroll
    for (int r = 0; r < 4; ++r) { s[r] = 0.f; ss[r] = 0.f; }
#pragma unroll
    for (int nl = 0; nl < 2; ++nl) {
      float bias = bp[cb + nl * 16 + row] + bn2[cb + nl * 16 + row];
#pragma unroll
      for (int r = 0; r < 4; ++r) {
        float v = fmaxf(acc2[m][nl][r] + bias, 0.0f);
        z[m][nl][r] = v;
        s[r] += v;
        ss[r] += v * v;
      }
    }
#pragma unroll
    for (int r = 0; r < 4; ++r) {
#pragma unroll
      for (int msk = 1; msk < 16; msk <<= 1) {
        s[r]  += __shfl_xor(s[r],  msk, 64);
        ss[r] += __shfl_xor(ss[r], msk, 64);
      }
      if (row == 0) part[m * 16 + quad * 4 + r][wave] = make_float2(s[r], ss[r]);
    }
  }
  __syncthreads();

#pragma unroll
  for (int m = 0; m < 4; ++m)
#pragma unroll
    for (int r = 0; r < 4; ++r) {
      int rr = m * 16 + quad * 4 + r;
      float2 p0 = part[rr][0], p1 = part[rr][1], p2 = part[rr][2], p3 = part[rr][3];
      float mean = (p0.x + p1.x + p2.x + p3.x) * (1.0f / 128.0f);
      float var  = (p0.y + p1.y + p2.y + p3.y) * (1.0f / 128.0f) - mean * mean;
      float rstd = rsqrtf(var + LN_EPS);
      int n = n0 + rr;
      if (n < H_N) {
#pragma unroll
        for (int nl = 0; nl < 2; ++nl) {
          int col = cb + nl * 16 + row;
          out[(size_t)n * 128 + col] =
              (z[m][nl][r] - mean) * rstd * gamma[col] + beta[col];
        }
      }
    }
}

// ---------------------------------------------------------------------------
extern "C" void kernel_launch(void* const* d_in, const int* in_sizes, int n_in,
                              void* d_out, int out_size, void* d_ws, size_t ws_size,
                              hipStream_t stream) {
  const float* x_h   = (const float*)d_in[0];
  const float* attr  = (const float*)d_in[1];
  const float* Wp    = (const float*)d_in[2];
  const float* bp    = (const float*)d_in[3];
  const float* We1   = (const float*)d_in[4];
  const float* be1   = (const float*)d_in[5];
  const float* We2   = (const float*)d_in[6];
  const float* be2   = (const float*)d_in[7];
  const float* Wn1   = (const float*)d_in[8];
  const float* bn1   = (const float*)d_in[9];
  const float* Wn2   = (const float*)d_in[10];
  const float* bn2   = (const float*)d_in[11];
  const float* gamma = (const float*)d_in[12];
  const float* beta  = (const float*)d_in[13];
  const int*   fg    = (const int*)d_in[14];
  const int*   res   = (const int*)d_in[15];
  float* out = (float*)d_out;

  // ---- workspace layout ----
  int* bcnt_e = (int*)d_ws;                                  // 8*NBUCK_E*16
  int* bcnt_h = bcnt_e + (size_t)8 * NBUCK_E * BCNT_PAD;     // 8*NBUCK_H*16
  unsigned* pairs_e = (unsigned*)(bcnt_h + (size_t)8 * NBUCK_H * BCNT_PAD);
  unsigned* pairs_h = pairs_e + (size_t)8 * NBUCK_E * SUBCAP_E;
  unsigned short* xh_bf    = (unsigned short*)(pairs_h + (size_t)8 * NBUCK_H * SUBCAP_H);
  unsigned short* edge_msg = xh_bf + (size_t)H_N * 128;
  short* w1  = (short*)(edge_msg + (size_t)E_N * 128);
  short* w2  = w1 + 128 * 192;
  short* wn1 = w2 + 128 * 128;
  short* wn2 = wn1 + 128 * 128;
  short* wp  = wn2 + 128 * 128;
  short* attr_bf = wp + 128 * 128;                           // E_N*64 bf16

  hipMemsetAsync(bcnt_e, 0,
                 (size_t)(8 * NBUCK_E + 8 * NBUCK_H) * BCNT_PAD * 4, stream);

  {
    int n4 = H_N * 128 / 4;
    k_cvt_bf16<<<(n4 + 255) / 256, 256, 0, stream>>>((const float4*)x_h, xh_bf, n4);
    n4 = E_N * 64 / 4;
    k_cvt_bf16<<<(n4 + 255) / 256, 256, 0, stream>>>((const float4*)attr, (unsigned short*)attr_bf, n4);
    n4 = 128 * 192 / 4;
    k_cvt_bf16<<<(n4 + 255) / 256, 256, 0, stream>>>((const float4*)We1, (unsigned short*)w1, n4);
    n4 = 128 * 128 / 4;
    k_cvt_bf16<<<(n4 + 255) / 256, 256, 0, stream>>>((const float4*)We2, (unsigned short*)w2, n4);
    k_cvt_bf16<<<(n4 + 255) / 256, 256, 0, stream>>>((const float4*)Wn1, (unsigned short*)wn1, n4);
    k_cvt_bf16<<<(n4 + 255) / 256, 256, 0, stream>>>((const float4*)Wn2, (unsigned short*)wn2, n4);
    k_cvt_bf16<<<(n4 + 255) / 256, 256, 0, stream>>>((const float4*)Wp, (unsigned short*)wp, n4);
  }

  k_bucket<<<(NI_N / 4 + 255) / 256, 256, 0, stream>>>(fg, res, bcnt_e, bcnt_h,
                                                       pairs_e, pairs_h);

  k_edge_fused<<<NBUCK_E, 256, 0, stream>>>(xh_bf, attr_bf, pairs_e, bcnt_e,
                                            w1, be1, w2, be2, edge_msg);
  k_node_fused<<<NBUCK_H, 256, 0, stream>>>(edge_msg, (const short*)xh_bf,
                                            pairs_h, bcnt_h,
                                            wp, bp, wn1, bn1, wn2, bn2,
                                            gamma, beta, out);
}

// Round 8
// 459.395 us; speedup vs baseline: 3.7856x; 1.0365x over previous
//
#include <hip/hip_runtime.h>

#define H_N   100000
#define E_N   200000
#define NI_N  1000000
#define LN_EPS 1e-5f

// Edge buckets: 64 edges each -> one MLP tile per bucket. 200000/64 = 3125 exactly.
#define NBUCK_E 3125
// Node buckets: 64 nodes each. ceil(100000/64) = 1563.
#define NBUCK_H 1563
#define SUBCAP_E 128       // per-XCD sub-bucket cap (mean 40, sigma ~6)
#define SUBCAP_H 192       // per-XCD sub-bucket cap (mean 80, sigma ~9)
#define CAP_E 512          // total per-bucket cap (mean 320, sigma ~18)
#define CAP_H 1024         // total per-bucket cap (mean 640, sigma ~25)
#define BCNT_PAD 16        // one counter per 64B line: kills same-line atomic RMW serialization

typedef __attribute__((ext_vector_type(8))) short bf16x8;
typedef __attribute__((ext_vector_type(4))) float floatx4;
typedef __attribute__((ext_vector_type(4))) int intx4;
typedef __attribute__((ext_vector_type(4))) unsigned uintx4;

__device__ inline unsigned short f2bf(float f) {
  unsigned u = __builtin_bit_cast(unsigned, f);
  u += 0x7fffu + ((u >> 16) & 1u);           // round-to-nearest-even
  return (unsigned short)(u >> 16);
}
__device__ inline float bf2f(unsigned short s) {
  unsigned u = ((unsigned)s) << 16;
  return __builtin_bit_cast(float, u);
}
__device__ inline unsigned get_xcc() {
  unsigned x;
  asm volatile("s_getreg_b32 %0, hwreg(HW_REG_XCC_ID)" : "=s"(x));
  return x & 7;
}

// ---------------------------------------------------------------------------
// Prep kernel: one launch does all fp32->bf16 conversions + bcnt zeroing.
// Block ranges: [0,12500) xh | [12500,25000) attr | [25000,25088) weights |
// [25088,25674) bcnt zero. Replaces memset + 7 cvt launches (launch-gap
// overhead was ~20-40us total).
// ---------------------------------------------------------------------------
#define PREP_XH_BLKS   12500   // H_N*128/4/256
#define PREP_ATTR_BLKS 12500   // E_N*64/4/256
#define PREP_W1_BLKS   24      // 128*192/4/256
#define PREP_W_BLKS    16      // 128*128/4/256
#define PREP_ZERO_BLKS 586     // (8*NBUCK_E+8*NBUCK_H)*BCNT_PAD/4/256
#define PREP_TOTAL (PREP_XH_BLKS + PREP_ATTR_BLKS + PREP_W1_BLKS + 4*PREP_W_BLKS + PREP_ZERO_BLKS)

__device__ inline void cvt4(const float4* __restrict__ src,
                            unsigned short* __restrict__ dst, int i, int n4) {
  if (i >= n4) return;
  float4 v = src[i];
  union { unsigned short us[4]; unsigned long long u64; } p;
  p.us[0] = f2bf(v.x); p.us[1] = f2bf(v.y);
  p.us[2] = f2bf(v.z); p.us[3] = f2bf(v.w);
  *(unsigned long long*)(dst + (size_t)i * 4) = p.u64;
}

__global__ __launch_bounds__(256) void k_prep(
    const float4* __restrict__ x_h, unsigned short* __restrict__ xh_bf,
    const float4* __restrict__ attr, unsigned short* __restrict__ attr_bf,
    const float4* __restrict__ We1, unsigned short* __restrict__ w1,
    const float4* __restrict__ We2, unsigned short* __restrict__ w2,
    const float4* __restrict__ Wn1, unsigned short* __restrict__ wn1,
    const float4* __restrict__ Wn2, unsigned short* __restrict__ wn2,
    const float4* __restrict__ Wp, unsigned short* __restrict__ wp,
    intx4* __restrict__ bcnt_zero) {
  int blk = blockIdx.x;
  int tid = threadIdx.x;
  if (blk < PREP_XH_BLKS) {
    cvt4(x_h, xh_bf, blk * 256 + tid, H_N * 128 / 4);
    return;
  }
  blk -= PREP_XH_BLKS;
  if (blk < PREP_ATTR_BLKS) {
    cvt4(attr, attr_bf, blk * 256 + tid, E_N * 64 / 4);
    return;
  }
  blk -= PREP_ATTR_BLKS;
  if (blk < PREP_W1_BLKS) {
    cvt4(We1, w1, blk * 256 + tid, 128 * 192 / 4);
    return;
  }
  blk -= PREP_W1_BLKS;
  if (blk < PREP_W_BLKS) {
    cvt4(We2, w2, blk * 256 + tid, 128 * 128 / 4);
    return;
  }
  blk -= PREP_W_BLKS;
  if (blk < PREP_W_BLKS) {
    cvt4(Wn1, wn1, blk * 256 + tid, 128 * 128 / 4);
    return;
  }
  blk -= PREP_W_BLKS;
  if (blk < PREP_W_BLKS) {
    cvt4(Wn2, wn2, blk * 256 + tid, 128 * 128 / 4);
    return;
  }
  blk -= PREP_W_BLKS;
  if (blk < PREP_W_BLKS) {
    cvt4(Wp, wp, blk * 256 + tid, 128 * 128 / 4);
    return;
  }
  blk -= PREP_W_BLKS;
  {
    int i = blk * 256 + tid;
    int n = (8 * NBUCK_E + 8 * NBUCK_H) * BCNT_PAD / 4;
    if (i < n) bcnt_zero[i] = (intx4){0, 0, 0, 0};
  }
}

// ---------------------------------------------------------------------------
// Bucket binning, XCD-local, 4 incidences/thread.
// ---------------------------------------------------------------------------
__global__ __launch_bounds__(256) void k_bucket(
    const int* __restrict__ fg, const int* __restrict__ res,
    int* __restrict__ bcnt_e, int* __restrict__ bcnt_h,
    unsigned* __restrict__ pairs_e, unsigned* __restrict__ pairs_h) {
  int i0 = (blockIdx.x * 256 + threadIdx.x) * 4;
  if (i0 >= NI_N) return;
  unsigned xcc = get_xcc();
  intx4 f4 = __builtin_nontemporal_load((const intx4*)(fg + i0));
  intx4 r4 = __builtin_nontemporal_load((const intx4*)(res + i0));
#pragma unroll
  for (int j = 0; j < 4; ++j) {
    int f = f4[j], r = r4[j];
    int be = r >> 6, se = r & 63;
    int pe = atomicAdd(bcnt_e + ((size_t)xcc * NBUCK_E + be) * BCNT_PAD, 1);
    if (pe < SUBCAP_E)
      __builtin_nontemporal_store(((unsigned)se << 24) | (unsigned)f,
          &pairs_e[((size_t)xcc * NBUCK_E + be) * SUBCAP_E + pe]);
    int bh = f >> 6, sh = f & 63;
    int ph = atomicAdd(bcnt_h + ((size_t)xcc * NBUCK_H + bh) * BCNT_PAD, 1);
    if (ph < SUBCAP_H)
      __builtin_nontemporal_store(((unsigned)sh << 24) | (unsigned)r,
          &pairs_h[((size_t)xcc * NBUCK_H + bh) * SUBCAP_H + ph]);
  }
}

// ---------------------------------------------------------------------------
// Quarter-owned-segment gather: each 16-lane quarter (qid = t>>4, 0..15)
// owns segments qid, qid+16, qid+32, qid+48 and walks ALL their entries:
// one dwordx4 load covers the full 256B row (lane ql = 16B slice). Loads
// within a quarter are independent; 4 quarters run concurrently -> >=8 rows
// in flight per wave even for short segments. No cross-quarter reduce.
// ---------------------------------------------------------------------------
#define GATHER_QSEG(basePtr)                                                   \
  {                                                                            \
    const int qid = (t >> 4);                                                  \
    for (int k = 0; k < 4; ++k) {                                              \
      int s = qid + 16 * k;                                                    \
      int o = cnts[s], e = cnts[s + 1];                                        \
      float a[8];                                                              \
      _Pragma("unroll")                                                        \
      for (int x = 0; x < 8; ++x) a[x] = 0.f;                                  \
      int j = o;                                                               \
      for (; j + 1 < e; j += 2) {                                              \
        unsigned off0 = sortedp[j], off1 = sortedp[j + 1];                     \
        uintx4 v0 = *(const uintx4*)((const char*)(basePtr) + off0 + ql * 16); \
        uintx4 v1 = *(const uintx4*)((const char*)(basePtr) + off1 + ql * 16); \
        _Pragma("unroll")                                                      \
        for (int x = 0; x < 4; ++x) {                                          \
          a[2 * x]     += bf2f((unsigned short)(v0[x] & 0xffffu)) +            \
                          bf2f((unsigned short)(v1[x] & 0xffffu));             \
          a[2 * x + 1] += bf2f((unsigned short)(v0[x] >> 16)) +                \
                          bf2f((unsigned short)(v1[x] >> 16));                 \
        }                                                                      \
      }                                                                        \
      if (j < e) {                                                             \
        unsigned off0 = sortedp[j];                                            \
        uintx4 v0 = *(const uintx4*)((const char*)(basePtr) + off0 + ql * 16); \
        _Pragma("unroll")                                                      \
        for (int x = 0; x < 4; ++x) {                                          \
          a[2 * x]     += bf2f((unsigned short)(v0[x] & 0xffffu));             \
          a[2 * x + 1] += bf2f((unsigned short)(v0[x] >> 16));                 \
        }                                                                      \
      }                                                                        \
      float inv = (e > o) ? 1.0f / (float)(e - o) : 0.0f;                      \
      uintx4 ov;                                                               \
      _Pragma("unroll")                                                        \
      for (int x = 0; x < 4; ++x)                                              \
        ov[x] = (unsigned)f2bf(a[2 * x] * inv) |                               \
                ((unsigned)f2bf(a[2 * x + 1] * inv) << 16);                    \
      *(uintx4*)&meanS[s][ql * 8] = ov;                                        \
    }                                                                          \
  }

// ---------------------------------------------------------------------------
// Fused edge: concat -> counting sort -> quarter-owned-segment gather-mean
// -> edge MLP. h1 overlays meanS (barrier-separated). LDS ~22KB, 6 blk/CU.
// ---------------------------------------------------------------------------
__global__ __launch_bounds__(256, 6) void k_edge_fused(
    const unsigned short* __restrict__ xh, const short* __restrict__ attr_bf,
    const unsigned* __restrict__ pairs, const int* __restrict__ bcnt,
    const short* __restrict__ w1, const float* __restrict__ b1,
    const short* __restrict__ w2, const float* __restrict__ b2,
    unsigned short* __restrict__ edge_msg) {
  __shared__ short meanS[64][136];     // 17408 B; doubles as h1 after barrier
  __shared__ unsigned raw[CAP_E];      // 2048
  __shared__ unsigned sortedp[CAP_E];  // 2048
  __shared__ int cnts[65];
  __shared__ int curs[64];
  short (*h1s)[136] = meanS;

  const int b = blockIdx.x;
  const int t = threadIdx.x;

  // ---- concat 8 per-XCD sub-lists ----
  int total = 0;
#pragma unroll
  for (int x = 0; x < 8; ++x) {
    int c = min(bcnt[((size_t)x * NBUCK_E + b) * BCNT_PAD], SUBCAP_E);
    const unsigned* src = pairs + ((size_t)x * NBUCK_E + b) * SUBCAP_E;
    for (int j = t; j < c; j += 256) {
      int d = total + j;
      if (d < CAP_E) raw[d] = src[j];
    }
    total += c;
  }
  const int cnt = min(total, CAP_E);
  if (t <= 64) cnts[t] = 0;
  __syncthreads();
  for (int j = t; j < cnt; j += 256)
    atomicAdd(&cnts[(raw[j] >> 24) + 1], 1);
  __syncthreads();
  for (int d = 1; d <= 64; d <<= 1) {
    int v = 0;
    if (t <= 64 && t >= d) v = cnts[t - d];
    __syncthreads();
    if (t <= 64) cnts[t] += v;
    __syncthreads();
  }
  if (t < 64) curs[t] = cnts[t];
  __syncthreads();
  for (int j = t; j < cnt; j += 256) {
    unsigned p = raw[j];
    int d = atomicAdd(&curs[p >> 24], 1);
    sortedp[d] = (p & 0xFFFFFFu) << 8;   // byte offset of 256B row
  }
  __syncthreads();

  // ---- quarter-owned-segment gather-mean into LDS tile ----
  const int wave = t >> 6, lane = t & 63;
  const int ql = lane & 15;
  GATHER_QSEG(xh);
  __syncthreads();

  // ---- edge MLP (A from LDS) ----
  const int row  = lane & 15;
  const int quad = lane >> 4;
  const int e0   = b * 64;
  const int cb   = wave * 32;

  bf16x8 B1[2][6];
#pragma unroll
  for (int nl = 0; nl < 2; ++nl)
#pragma unroll
    for (int ks = 0; ks < 6; ++ks)
      B1[nl][ks] = *(const bf16x8*)(w1 + (size_t)(cb + nl * 16 + row) * 192 +
                                    ks * 32 + quad * 8);

  floatx4 acc[4][2];
#pragma unroll
  for (int m = 0; m < 4; ++m)
#pragma unroll
    for (int nl = 0; nl < 2; ++nl) acc[m][nl] = (floatx4){0.f, 0.f, 0.f, 0.f};

#pragma unroll
  for (int ks = 0; ks < 6; ++ks) {
    bf16x8 a[4];
#pragma unroll
    for (int m = 0; m < 4; ++m) {
      if (ks < 4) {
        a[m] = *(const bf16x8*)&meanS[m * 16 + row][ks * 32 + quad * 8];
      } else {
        int e = e0 + m * 16 + row;
        a[m] = *(const bf16x8*)(attr_bf + (size_t)e * 64 + (ks - 4) * 32 + quad * 8);
      }
    }
#pragma unroll
    for (int m = 0; m < 4; ++m)
#pragma unroll
      for (int nl = 0; nl < 2; ++nl)
        acc[m][nl] = __builtin_amdgcn_mfma_f32_16x16x32_bf16(a[m], B1[nl][ks],
                                                             acc[m][nl], 0, 0, 0);
  }
  __syncthreads();   // all meanS reads done before h1 overlay writes

#pragma unroll
  for (int nl = 0; nl < 2; ++nl) {
    float bias = b1[cb + nl * 16 + row];
#pragma unroll
    for (int m = 0; m < 4; ++m)
#pragma unroll
      for (int r = 0; r < 4; ++r)
        h1s[m * 16 + quad * 4 + r][cb + nl * 16 + row] =
            (short)f2bf(fmaxf(acc[m][nl][r] + bias, 0.0f));
  }

  bf16x8 B2[2][4];
#pragma unroll
  for (int nl = 0; nl < 2; ++nl)
#pragma unroll
    for (int ks = 0; ks < 4; ++ks)
      B2[nl][ks] = *(const bf16x8*)(w2 + (size_t)(cb + nl * 16 + row) * 128 +
                                    ks * 32 + quad * 8);
  __syncthreads();

  floatx4 acc2[4][2];
#pragma unroll
  for (int m = 0; m < 4; ++m)
#pragma unroll
    for (int nl = 0; nl < 2; ++nl) acc2[m][nl] = (floatx4){0.f, 0.f, 0.f, 0.f};

#pragma unroll
  for (int ks = 0; ks < 4; ++ks) {
    bf16x8 a[4];
#pragma unroll
    for (int m = 0; m < 4; ++m)
      a[m] = *(const bf16x8*)&h1s[m * 16 + row][ks * 32 + quad * 8];
#pragma unroll
    for (int m = 0; m < 4; ++m)
#pragma unroll
      for (int nl = 0; nl < 2; ++nl)
        acc2[m][nl] = __builtin_amdgcn_mfma_f32_16x16x32_bf16(a[m], B2[nl][ks],
                                                              acc2[m][nl], 0, 0, 0);
  }

#pragma unroll
  for (int nl = 0; nl < 2; ++nl) {
    int col = cb + nl * 16 + row;
    float bias = b2[col];
#pragma unroll
    for (int m = 0; m < 4; ++m)
#pragma unroll
      for (int r = 0; r < 4; ++r)
        edge_msg[(size_t)(e0 + m * 16 + quad * 4 + r) * 128 + col] =
            f2bf(acc2[m][nl][r] + bias);
  }
}

// ---------------------------------------------------------------------------
// Fused node: quarter-owned-segment gather on edge_msg rows + node MLP + LN.
// LDS ~26.1KB -> 5 blocks/CU: h1 overlays meanS, part overlays raw.
// ---------------------------------------------------------------------------
__global__ __launch_bounds__(256, 5) void k_node_fused(
    const unsigned short* __restrict__ emsg, const short* __restrict__ xh_bf,
    const unsigned* __restrict__ pairs, const int* __restrict__ bcnt,
    const short* __restrict__ wp, const float* __restrict__ bp,
    const short* __restrict__ wn1, const float* __restrict__ bn1,
    const short* __restrict__ wn2, const float* __restrict__ bn2,
    const float* __restrict__ gamma, const float* __restrict__ beta,
    float* __restrict__ out) {
  __shared__ short meanS[64][136];     // 17408 B; doubles as h1
  __shared__ unsigned raw[CAP_H];      // 4096 B; doubles as part[64][4] (2048 B)
  __shared__ unsigned sortedp[CAP_H];  // 4096
  __shared__ int cnts[65];
  __shared__ int curs[64];
  short (*h1s)[136] = meanS;
  float2 (*part)[4] = (float2(*)[4])raw;

  const int b = blockIdx.x;
  const int t = threadIdx.x;

  int total = 0;
#pragma unroll
  for (int x = 0; x < 8; ++x) {
    int c = min(bcnt[((size_t)x * NBUCK_H + b) * BCNT_PAD], SUBCAP_H);
    const unsigned* src = pairs + ((size_t)x * NBUCK_H + b) * SUBCAP_H;
    for (int j = t; j < c; j += 256) {
      int d = total + j;
      if (d < CAP_H) raw[d] = src[j];
    }
    total += c;
  }
  const int cnt = min(total, CAP_H);
  if (t <= 64) cnts[t] = 0;
  __syncthreads();
  for (int j = t; j < cnt; j += 256)
    atomicAdd(&cnts[(raw[j] >> 24) + 1], 1);
  __syncthreads();
  for (int d = 1; d <= 64; d <<= 1) {
    int v = 0;
    if (t <= 64 && t >= d) v = cnts[t - d];
    __syncthreads();
    if (t <= 64) cnts[t] += v;
    __syncthreads();
  }
  if (t < 64) curs[t] = cnts[t];
  __syncthreads();
  for (int j = t; j < cnt; j += 256) {
    unsigned p = raw[j];
    int d = atomicAdd(&curs[p >> 24], 1);
    sortedp[d] = (p & 0xFFFFFFu) << 8;   // byte offset of 256B row
  }
  __syncthreads();

  const int wave = t >> 6, lane = t & 63;
  const int ql = lane & 15;
  GATHER_QSEG(emsg);
  __syncthreads();

  // ---- node MLP + LN (A from LDS) ----
  const int row  = lane & 15;
  const int quad = lane >> 4;
  const int n0   = b * 64;
  const int cb   = wave * 32;

  bf16x8 B1[2][4];
#pragma unroll
  for (int nl = 0; nl < 2; ++nl)
#pragma unroll
    for (int ks = 0; ks < 4; ++ks)
      B1[nl][ks] = *(const bf16x8*)(wn1 + (size_t)(cb + nl * 16 + row) * 128 +
                                    ks * 32 + quad * 8);

  floatx4 acc[4][2];
#pragma unroll
  for (int m = 0; m < 4; ++m)
#pragma unroll
    for (int nl = 0; nl < 2; ++nl) acc[m][nl] = (floatx4){0.f, 0.f, 0.f, 0.f};

#pragma unroll
  for (int ks = 0; ks < 4; ++ks) {
    bf16x8 a[4];
#pragma unroll
    for (int m = 0; m < 4; ++m)
      a[m] = *(const bf16x8*)&meanS[m * 16 + row][ks * 32 + quad * 8];
#pragma unroll
    for (int m = 0; m < 4; ++m)
#pragma unroll
      for (int nl = 0; nl < 2; ++nl)
        acc[m][nl] = __builtin_amdgcn_mfma_f32_16x16x32_bf16(a[m], B1[nl][ks],
                                                             acc[m][nl], 0, 0, 0);
  }
  __syncthreads();   // all meanS reads done before h1 overlay writes

#pragma unroll
  for (int nl = 0; nl < 2; ++nl) {
    float bias = bn1[cb + nl * 16 + row];
#pragma unroll
    for (int m = 0; m < 4; ++m)
#pragma unroll
      for (int r = 0; r < 4; ++r)
        h1s[m * 16 + quad * 4 + r][cb + nl * 16 + row] =
            (short)f2bf(fmaxf(acc[m][nl][r] + bias, 0.0f));
  }

  bf16x8 B2[2][4], Bp[2][4];
#pragma unroll
  for (int nl = 0; nl < 2; ++nl)
#pragma unroll
    for (int ks = 0; ks < 4; ++ks) {
      B2[nl][ks] = *(const bf16x8*)(wn2 + (size_t)(cb + nl * 16 + row) * 128 +
                                    ks * 32 + quad * 8);
      Bp[nl][ks] = *(const bf16x8*)(wp + (size_t)(cb + nl * 16 + row) * 128 +
                                    ks * 32 + quad * 8);
    }
  __syncthreads();

  floatx4 acc2[4][2];
#pragma unroll
  for (int m = 0; m < 4; ++m)
#pragma unroll
    for (int nl = 0; nl < 2; ++nl) acc2[m][nl] = (floatx4){0.f, 0.f, 0.f, 0.f};

#pragma unroll
  for (int ks = 0; ks < 4; ++ks) {
    bf16x8 at[4], ax[4];
#pragma unroll
    for (int m = 0; m < 4; ++m) {
      at[m] = *(const bf16x8*)&h1s[m * 16 + row][ks * 32 + quad * 8];
      int n = n0 + m * 16 + row;
      ax[m] = *(const bf16x8*)(xh_bf + (size_t)n * 128 + ks * 32 + quad * 8);
    }
#pragma unroll
    for (int m = 0; m < 4; ++m)
#pragma unroll
      for (int nl = 0; nl < 2; ++nl) {
        acc2[m][nl] = __builtin_amdgcn_mfma_f32_16x16x32_bf16(at[m], B2[nl][ks],
                                                              acc2[m][nl], 0, 0, 0);
        acc2[m][nl] = __builtin_amdgcn_mfma_f32_16x16x32_bf16(ax[m], Bp[nl][ks],
                                                              acc2[m][nl], 0, 0, 0);
      }
  }

  float z[4][2][4];
#pragma unroll
  for (int m = 0; m < 4; ++m) {
    float s[4], ss[4];
#pragma unroll
    for (int r = 0; r < 4; ++r) { s[r] = 0.f; ss[r] = 0.f; }
#pragma unroll
    for (int nl = 0; nl < 2; ++nl) {
      float bias = bp[cb + nl * 16 + row] + bn2[cb + nl * 16 + row];
#pragma unroll
      for (int r = 0; r < 4; ++r) {
        float v = fmaxf(acc2[m][nl][r] + bias, 0.0f);
        z[m][nl][r] = v;
        s[r] += v;
        ss[r] += v * v;
      }
    }
#pragma unroll
    for (int r = 0; r < 4; ++r) {
#pragma unroll
      for (int msk = 1; msk < 16; msk <<= 1) {
        s[r]  += __shfl_xor(s[r],  msk, 64);
        ss[r] += __shfl_xor(ss[r], msk, 64);
      }
      if (row == 0) part[m * 16 + quad * 4 + r][wave] = make_float2(s[r], ss[r]);
    }
  }
  __syncthreads();

#pragma unroll
  for (int m = 0; m < 4; ++m)
#pragma unroll
    for (int r = 0; r < 4; ++r) {
      int rr = m * 16 + quad * 4 + r;
      float2 p0 = part[rr][0], p1 = part[rr][1], p2 = part[rr][2], p3 = part[rr][3];
      float mean = (p0.x + p1.x + p2.x + p3.x) * (1.0f / 128.0f);
      float var  = (p0.y + p1.y + p2.y + p3.y) * (1.0f / 128.0f) - mean * mean;
      float rstd = rsqrtf(var + LN_EPS);
      int n = n0 + rr;
      if (n < H_N) {
#pragma unroll
        for (int nl = 0; nl < 2; ++nl) {
          int col = cb + nl * 16 + row;
          out[(size_t)n * 128 + col] =
              (z[m][nl][r] - mean) * rstd * gamma[col] + beta[col];
        }
      }
    }
}

// ---------------------------------------------------------------------------
extern "C" void kernel_launch(void* const* d_in, const int* in_sizes, int n_in,
                              void* d_out, int out_size, void* d_ws, size_t ws_size,
                              hipStream_t stream) {
  const float* x_h   = (const float*)d_in[0];
  const float* attr  = (const float*)d_in[1];
  const float* Wp    = (const float*)d_in[2];
  const float* bp    = (const float*)d_in[3];
  const float* We1   = (const float*)d_in[4];
  const float* be1   = (const float*)d_in[5];
  const float* We2   = (const float*)d_in[6];
  const float* be2   = (const float*)d_in[7];
  const float* Wn1   = (const float*)d_in[8];
  const float* bn1   = (const float*)d_in[9];
  const float* Wn2   = (const float*)d_in[10];
  const float* bn2   = (const float*)d_in[11];
  const float* gamma = (const float*)d_in[12];
  const float* beta  = (const float*)d_in[13];
  const int*   fg    = (const int*)d_in[14];
  const int*   res   = (const int*)d_in[15];
  float* out = (float*)d_out;

  // ---- workspace layout ----
  int* bcnt_e = (int*)d_ws;                                  // 8*NBUCK_E*16
  int* bcnt_h = bcnt_e + (size_t)8 * NBUCK_E * BCNT_PAD;     // 8*NBUCK_H*16
  unsigned* pairs_e = (unsigned*)(bcnt_h + (size_t)8 * NBUCK_H * BCNT_PAD);
  unsigned* pairs_h = pairs_e + (size_t)8 * NBUCK_E * SUBCAP_E;
  unsigned short* xh_bf    = (unsigned short*)(pairs_h + (size_t)8 * NBUCK_H * SUBCAP_H);
  unsigned short* edge_msg = xh_bf + (size_t)H_N * 128;
  short* w1  = (short*)(edge_msg + (size_t)E_N * 128);
  short* w2  = w1 + 128 * 192;
  short* wn1 = w2 + 128 * 128;
  short* wn2 = wn1 + 128 * 128;
  short* wp  = wn2 + 128 * 128;
  short* attr_bf = wp + 128 * 128;                           // E_N*64 bf16

  k_prep<<<PREP_TOTAL, 256, 0, stream>>>(
      (const float4*)x_h, xh_bf,
      (const float4*)attr, (unsigned short*)attr_bf,
      (const float4*)We1, (unsigned short*)w1,
      (const float4*)We2, (unsigned short*)w2,
      (const float4*)Wn1, (unsigned short*)wn1,
      (const float4*)Wn2, (unsigned short*)wn2,
      (const float4*)Wp, (unsigned short*)wp,
      (intx4*)bcnt_e);

  k_bucket<<<(NI_N / 4 + 255) / 256, 256, 0, stream>>>(fg, res, bcnt_e, bcnt_h,
                                                       pairs_e, pairs_h);

  k_edge_fused<<<NBUCK_E, 256, 0, stream>>>(xh_bf, attr_bf, pairs_e, bcnt_e,
                                            w1, be1, w2, be2, edge_msg);
  k_node_fused<<<NBUCK_H, 256, 0, stream>>>(edge_msg, (const short*)xh_bf,
                                            pairs_h, bcnt_h,
                                            wp, bp, wn1, bn1, wn2, bn2,
                                            gamma, beta, out);
}